// Round 5
// baseline (2081.887 us; speedup 1.0000x reference)
//
#include <hip/hip_runtime.h>
#include <cstdint>
#include <cmath>

// Problem constants
static constexpr int V_  = 50000;
static constexpr int E_  = 300;
static constexpr int C_  = 128;
static constexpr int B_  = 128;
static constexpr int SC_ = 512;
static constexpr int SE_ = 64;
static constexpr int NCOL = 768;   // [fw_gate 256 | fw_cand 128 | bw_gate 256 | bw_cand 128]
static constexpr int KP  = 320;    // K padded to 10 x 32 for MFMA

// ws layout (float offsets)
static constexpr size_t OFF_PROJ  = 0;
static constexpr size_t SZ_PROJ   = (size_t)V_ * NCOL;
static constexpr size_t OFF_WXP   = OFF_PROJ + SZ_PROJ;
static constexpr size_t SZ_WXP    = (size_t)304 * NCOL;
static constexpr size_t OFF_UALL  = OFF_WXP + SZ_WXP;
static constexpr size_t SZ_UALL   = (size_t)C_ * NCOL;
static constexpr size_t OFF_BIAS  = OFF_UALL + SZ_UALL;
static constexpr size_t SZ_BIAS   = NCOL;
static constexpr size_t OFF_ST    = OFF_BIAS + SZ_BIAS;
static constexpr size_t SZ_ST_CTX = (size_t)B_ * SC_ * C_;
static constexpr size_t SZ_ST_END = (size_t)B_ * SE_ * C_;
static constexpr size_t SZ_ST     = 2*SZ_ST_CTX + 2*SZ_ST_END;    // 75.5 MB
static constexpr size_t OFF_FEATS = OFF_ST + SZ_ST;
static constexpr size_t SZ_FEATS  = (size_t)B_ * 512;
static constexpr size_t OFF_BT    = OFF_FEATS + SZ_FEATS;
static constexpr size_t SZ_BT     = (size_t)NCOL * KP / 2 * 2;    // 2 short arrays
static constexpr size_t OFF_AWT   = OFF_BT + SZ_BT;               // att_w^T hi/lo shorts
// A_hi/A_lo (bf16) OVERLAP the states region (dead once gemm ends; recur
// zeroes its own tail rows so no global memset is needed).

typedef __attribute__((ext_vector_type(8))) short bf16x8;
typedef __attribute__((ext_vector_type(4))) float f32x4;

static __device__ __forceinline__ unsigned short f2bf_rne(float f) {
  unsigned u = __float_as_uint(f);
  unsigned r = u + 0x7fffu + ((u >> 16) & 1u);
  return (unsigned short)(r >> 16);
}

static __device__ __forceinline__ void gload_lds16(const short* g, short* l) {
  __builtin_amdgcn_global_load_lds(
      (const __attribute__((address_space(1))) void*)g,
      (__attribute__((address_space(3))) void*)l, 16, 0, 0);
}

// fast activations: __expf + v_rcp_f32 (~1e-6 rel err; logit threshold 7.4e-5)
static __device__ __forceinline__ float fast_sigmoid(float x) {
  return __builtin_amdgcn_rcpf(1.f + __expf(-x));
}
static __device__ __forceinline__ float fast_tanh(float x) {
  return fmaf(-2.f, __builtin_amdgcn_rcpf(__expf(2.f * x) + 1.f), 1.f);
}

// ---------------------------------------------------------------------------
// Pack: Wxp[304][768] fp32, Uall[128][768], bias[768]
// ---------------------------------------------------------------------------
__global__ void pack_kernel(const float* __restrict__ fw_gw, const float* __restrict__ fw_gb,
                            const float* __restrict__ fw_cw, const float* __restrict__ fw_cb,
                            const float* __restrict__ bw_gw, const float* __restrict__ bw_gb,
                            const float* __restrict__ bw_cw, const float* __restrict__ bw_cb,
                            float* __restrict__ ws) {
  int i = blockIdx.x * 256 + threadIdx.x;
  float* Wxp  = ws + OFF_WXP;
  float* Uall = ws + OFF_UALL;
  float* bias = ws + OFF_BIAS;
  if (i < 304 * NCOL) {
    int k = i / NCOL, c = i % NCOL;
    float v = 0.f;
    if (k < 300) {
      if (c < 256)      v = fw_gw[k*256 + c];
      else if (c < 384) v = fw_cw[k*128 + (c-256)];
      else if (c < 640) v = bw_gw[k*256 + (c-384)];
      else              v = bw_cw[k*128 + (c-640)];
    }
    Wxp[i] = v;
    return;
  }
  int j = i - 304 * NCOL;
  if (j >= 0 && j < 128 * NCOL) {
    int k = j / NCOL, c = j % NCOL;
    int kk = 300 + k;
    float v;
    if (c < 256)      v = fw_gw[kk*256 + c];
    else if (c < 384) v = fw_cw[kk*128 + (c-256)];
    else if (c < 640) v = bw_gw[kk*256 + (c-384)];
    else              v = bw_cw[kk*128 + (c-640)];
    Uall[j] = v;
    return;
  }
  int m = j - 128 * NCOL;
  if (m >= 0 && m < NCOL) {
    float v;
    if (m < 256)      v = fw_gb[m];
    else if (m < 384) v = fw_cb[m-256];
    else if (m < 640) v = bw_gb[m-384];
    else              v = bw_cb[m-640];
    bias[m] = v;
  }
}

// Bt hi/lo for the proj GEMM + att_w^T hi/lo for the MFMA attention
__global__ void pack_bt(const float* __restrict__ Wxp, short* __restrict__ Bthi,
                        short* __restrict__ Btlo, const float* __restrict__ att_w,
                        short* __restrict__ awt_hi, short* __restrict__ awt_lo) {
  int i = blockIdx.x * 256 + threadIdx.x;
  if (i < NCOL * KP) {
    int k = i % KP, n = i / KP;
    float v = (k < 304) ? Wxp[(size_t)k * NCOL + n] : 0.f;
    unsigned short h = f2bf_rne(v);
    float hf = __uint_as_float((unsigned)h << 16);
    unsigned short lo = f2bf_rne(v - hf);
    Bthi[i] = (short)h;
    Btlo[i] = (short)lo;
    return;
  }
  int j = i - NCOL * KP;
  if (j < 128 * 128) {
    int d = j >> 7, c = j & 127;
    float v = att_w[(size_t)c * 128 + d];   // transpose: awt[d][k=c]
    unsigned short h = f2bf_rne(v);
    float hf = __uint_as_float((unsigned)h << 16);
    unsigned short lo = f2bf_rne(v - hf);
    awt_hi[j] = (short)h;
    awt_lo[j] = (short)lo;
  }
}

__global__ void pack_emb(const float* __restrict__ emb, short* __restrict__ Ahi,
                         short* __restrict__ Alo) {
  size_t i = (size_t)blockIdx.x * 256 + threadIdx.x;
  if (i >= (size_t)V_ * KP) return;
  int k = (int)(i % KP);
  size_t row = i / KP;
  float v = (k < E_) ? emb[row * E_ + k] : 0.f;
  unsigned short h = f2bf_rne(v);
  float hf = __uint_as_float((unsigned)h << 16);
  unsigned short lo = f2bf_rne(v - hf);
  Ahi[i] = (short)h;
  Alo[i] = (short)lo;
}

// ---------------------------------------------------------------------------
// proj = emb @ Wxp via bf16x3 split MFMA (m97 structure). Linear grid +
// bijective XCD swizzle (m204): all 6 n-blocks of one m-tile on one XCD.
// ---------------------------------------------------------------------------
__global__ __launch_bounds__(256) void gemm_mfma(
    const short* __restrict__ Ahi, const short* __restrict__ Alo,
    const short* __restrict__ Bthi, const short* __restrict__ Btlo,
    float* __restrict__ proj) {
  __shared__ short lds[16384];
  int tid = threadIdx.x, wid = tid >> 6, lane = tid & 63;

  // bijective XCD swizzle: nwg=2346, q=293, r=2
  int bid = blockIdx.x;
  int xcd = bid & 7, idx = bid >> 3;
  int wgid = (xcd < 2 ? xcd * 294 : 588 + (xcd - 2) * 293) + idx;
  int m0 = (wgid / 6) * 128;
  int n0 = (wgid % 6) * 128;

  f32x4 acc[4][4] = {};

  int lr = lane >> 2, lc = lane & 3;
  int q0 = wid * 2, q1 = q0 + 1;
  int r0 = q0 * 16 + lr, r1 = q1 * 16 + lr;
  int am0 = m0 + r0; if (am0 > V_ - 1) am0 = V_ - 1;
  int am1 = m0 + r1; if (am1 > V_ - 1) am1 = V_ - 1;
  size_t gaOff0 = (size_t)am0 * KP + lc * 8;
  size_t gaOff1 = (size_t)am1 * KP + lc * 8;
  size_t gbOff0 = (size_t)(n0 + r0) * KP + lc * 8;
  size_t gbOff1 = (size_t)(n0 + r1) * KP + lc * 8;

  int quad = lane >> 4;
  int arow = (wid >> 1) * 64 + (lane & 15);
  int brow = (wid & 1) * 64 + (lane & 15);

  for (int k0 = 0; k0 < KP; k0 += 32) {
    gload_lds16(Ahi  + gaOff0 + k0, lds +         q0 * 512);
    gload_lds16(Ahi  + gaOff1 + k0, lds +         q1 * 512);
    gload_lds16(Alo  + gaOff0 + k0, lds +  4096 + q0 * 512);
    gload_lds16(Alo  + gaOff1 + k0, lds +  4096 + q1 * 512);
    gload_lds16(Bthi + gbOff0 + k0, lds +  8192 + q0 * 512);
    gload_lds16(Bthi + gbOff1 + k0, lds +  8192 + q1 * 512);
    gload_lds16(Btlo + gbOff0 + k0, lds + 12288 + q0 * 512);
    gload_lds16(Btlo + gbOff1 + k0, lds + 12288 + q1 * 512);
    __syncthreads();

    bf16x8 ah[4], al[4], bh[4], bl[4];
#pragma unroll
    for (int i = 0; i < 4; ++i) {
      ah[i] = *(bf16x8*)&lds[        (arow + i*16) * 32 + quad * 8];
      al[i] = *(bf16x8*)&lds[ 4096 + (arow + i*16) * 32 + quad * 8];
      bh[i] = *(bf16x8*)&lds[ 8192 + (brow + i*16) * 32 + quad * 8];
      bl[i] = *(bf16x8*)&lds[12288 + (brow + i*16) * 32 + quad * 8];
    }
#pragma unroll
    for (int i = 0; i < 4; ++i)
#pragma unroll
      for (int j = 0; j < 4; ++j) {
        acc[i][j] = __builtin_amdgcn_mfma_f32_16x16x32_bf16(ah[i], bh[j], acc[i][j], 0, 0, 0);
        acc[i][j] = __builtin_amdgcn_mfma_f32_16x16x32_bf16(ah[i], bl[j], acc[i][j], 0, 0, 0);
        acc[i][j] = __builtin_amdgcn_mfma_f32_16x16x32_bf16(al[i], bh[j], acc[i][j], 0, 0, 0);
      }
    __syncthreads();
  }

  int colb = n0 + (wid & 1) * 64 + (lane & 15);
  int rowb = m0 + (wid >> 1) * 64 + quad * 4;
#pragma unroll
  for (int i = 0; i < 4; ++i) {
    int rb = rowb + i * 16;
#pragma unroll
    for (int j = 0; j < 4; ++j) {
      int cc = colb + j * 16;
#pragma unroll
      for (int r = 0; r < 4; ++r) {
        int rr = rb + r;
        if (rr < V_) proj[(size_t)rr * NCOL + cc] = acc[i][j][r];
      }
    }
  }
}

// ---------------------------------------------------------------------------
// Recurrence v4: MFMA-batched, 16 same-direction chains per WG, 32 WGs.
// Per step: gate [16x128]@[128x256] (192 mfma, bf16x3) + cand [16x128]@
// [128x128] (96 mfma) split over 4 waves; weights live in registers as
// B-frags (loaded once from Uall); h / r*h staged in LDS as A-frags
// (hi/lo bf16, k-tiled [kt][row][32] like the gemm layout). 2 barriers/step.
// Frag mappings copied from the verified gemm: A lane=(row=l&15,k=quad*8),
// B lane=(col=l&15,k=quad*8), C (row=(l>>4)*4+reg, col=l&15).
// ---------------------------------------------------------------------------
__global__ __attribute__((amdgpu_flat_work_group_size(256, 256),
                          amdgpu_waves_per_eu(1, 1)))
void recur_mfma_kernel(
    const int* __restrict__ ctx, const int* __restrict__ endseq,
    const int* __restrict__ ctx_len, const int* __restrict__ end_len,
    const float* __restrict__ proj, const float* __restrict__ Uall,
    const float* __restrict__ bias, float* __restrict__ states) {
  __shared__ __align__(16) short hAh[4][16][32];
  __shared__ __align__(16) short hAl[4][16][32];
  __shared__ __align__(16) short rAh[4][16][32];
  __shared__ __align__(16) short rAl[4][16][32];
  __shared__ __align__(16) float h_f[16][132];
  __shared__ __align__(16) float u_f[16][132];

  int g = blockIdx.x, tid = threadIdx.x;
  int w = tid >> 6, lane = tid & 63, quad = lane >> 4, l15 = lane & 15;

  // g: 0-7 ctx/fw, 8-15 ctx/bw, 16-23 end/fw, 24-31 end/bw
  int isEnd = (g >> 4) & 1, dir = (g >> 3) & 1;
  int b0 = (g & 7) * 16;
  int S = isEnd ? SE_ : SC_;
  const int* seqarr = isEnd ? endseq : ctx;
  const int* lenarr = isEnd ? end_len : ctx_len;
  float* stroot = states + (isEnd ? (2*SZ_ST_CTX + (dir ? SZ_ST_END : 0))
                                  : (dir ? SZ_ST_CTX : 0));
  int dirOff = dir ? 384 : 0;

  // this lane's 4 chains: rows quad*4+r
  const int* seqp[4]; int Lr[4]; float* stb[4];
#pragma unroll
  for (int r = 0; r < 4; ++r) {
    int b = b0 + quad*4 + r;
    seqp[r] = seqarr + b * S;
    Lr[r]   = lenarr[b];
    stb[r]  = stroot + (size_t)b * S * C_;
  }
  int Lm = Lr[0];
#pragma unroll
  for (int r = 1; r < 4; ++r) Lm = (Lr[r] > Lm) ? Lr[r] : Lm;
  { int o = __shfl_xor(Lm, 16, 64); Lm = (o > Lm) ? o : Lm; }
  { int o = __shfl_xor(Lm, 32, 64); Lm = (o > Lm) ? o : Lm; }

  // columns owned by this lane
  int colg[4], colc[2];
#pragma unroll
  for (int tt = 0; tt < 4; ++tt) colg[tt] = w*64 + tt*16 + l15;
#pragma unroll
  for (int tt = 0; tt < 2; ++tt) colc[tt] = w*32 + tt*16 + l15;

  // B-frags (weights) in registers: gate 32 frags, cand 16 frags
  bf16x8 gBh[4][4], gBl[4][4], cBh[2][4], cBl[2][4];
#pragma unroll
  for (int tt = 0; tt < 4; ++tt)
#pragma unroll
    for (int kt = 0; kt < 4; ++kt) {
      short h8[8], l8[8];
#pragma unroll
      for (int j = 0; j < 8; ++j) {
        float v = Uall[(size_t)(kt*32 + quad*8 + j) * NCOL + dirOff + colg[tt]];
        unsigned short hh = f2bf_rne(v);
        float hf = __uint_as_float((unsigned)hh << 16);
        h8[j] = (short)hh;
        l8[j] = (short)f2bf_rne(v - hf);
      }
      gBh[tt][kt] = *(bf16x8*)h8;
      gBl[tt][kt] = *(bf16x8*)l8;
    }
#pragma unroll
  for (int tt = 0; tt < 2; ++tt)
#pragma unroll
    for (int kt = 0; kt < 4; ++kt) {
      short h8[8], l8[8];
#pragma unroll
      for (int j = 0; j < 8; ++j) {
        float v = Uall[(size_t)(kt*32 + quad*8 + j) * NCOL + dirOff + 256 + colc[tt]];
        unsigned short hh = f2bf_rne(v);
        float hf = __uint_as_float((unsigned)hh << 16);
        h8[j] = (short)hh;
        l8[j] = (short)f2bf_rne(v - hf);
      }
      cBh[tt][kt] = *(bf16x8*)h8;
      cBl[tt][kt] = *(bf16x8*)l8;
    }

  float bg[4], bc[2];
#pragma unroll
  for (int tt = 0; tt < 4; ++tt) bg[tt] = bias[dirOff + colg[tt]];
#pragma unroll
  for (int tt = 0; tt < 2; ++tt) bc[tt] = bias[dirOff + 256 + colc[tt]];

  // zero state
  for (int i = tid; i < 16*132; i += 256) ((float*)h_f)[i] = 0.f;
  for (int i = tid; i < 4*16*32; i += 256) {
    ((short*)hAh)[i] = 0; ((short*)hAl)[i] = 0;
  }
  __syncthreads();

  auto load_x = [&](int stp, float (&XG)[4][4], float (&XC)[2][4]) {
#pragma unroll
    for (int r = 0; r < 4; ++r) {
      int L = Lr[r];
      int pos = (stp < L) ? (dir ? (L - 1 - stp) : stp) : 0;
      int tok = seqp[r][pos];
      const float* xr = proj + (size_t)tok * NCOL + dirOff;
#pragma unroll
      for (int tt = 0; tt < 4; ++tt) XG[tt][r] = xr[colg[tt]];
#pragma unroll
      for (int tt = 0; tt < 2; ++tt) XC[tt][r] = xr[256 + colc[tt]];
    }
  };

  float xg[4][4], xc[2][4], xgn[4][4], xcn[2][4];
  load_x(0, xg, xc);

  for (int t = 0; t < Lm; ++t) {
    load_x(t + 1, xgn, xcn);   // prefetch (clamped; dead values unused)

    // gate MFMA: acc[tt] covers cols w*64 + tt*16 (+l15)
    f32x4 ag[4] = {};
#pragma unroll
    for (int kt = 0; kt < 4; ++kt) {
      bf16x8 Ah = *(bf16x8*)&hAh[kt][l15][quad*8];
      bf16x8 Al = *(bf16x8*)&hAl[kt][l15][quad*8];
#pragma unroll
      for (int tt = 0; tt < 4; ++tt)
        ag[tt] = __builtin_amdgcn_mfma_f32_16x16x32_bf16(Ah, gBh[tt][kt], ag[tt], 0, 0, 0);
#pragma unroll
      for (int tt = 0; tt < 4; ++tt)
        ag[tt] = __builtin_amdgcn_mfma_f32_16x16x32_bf16(Ah, gBl[tt][kt], ag[tt], 0, 0, 0);
#pragma unroll
      for (int tt = 0; tt < 4; ++tt)
        ag[tt] = __builtin_amdgcn_mfma_f32_16x16x32_bf16(Al, gBh[tt][kt], ag[tt], 0, 0, 0);
    }

    // gate epilogue: waves 0,1 produce r*h A-frags; waves 2,3 publish u
    if (w < 2) {
#pragma unroll
      for (int tt = 0; tt < 4; ++tt) {
        int col = colg[tt];            // 0..127
        int kt2 = col >> 5, kk = col & 31;
#pragma unroll
        for (int r = 0; r < 4; ++r) {
          int row = quad*4 + r;
          float gg = fast_sigmoid(ag[tt][r] + xg[tt][r] + bg[tt]);
          float rh = gg * h_f[row][col];
          unsigned short hi = f2bf_rne(rh);
          float hf = __uint_as_float((unsigned)hi << 16);
          rAh[kt2][row][kk] = (short)hi;
          rAl[kt2][row][kk] = (short)f2bf_rne(rh - hf);
        }
      }
    } else {
#pragma unroll
      for (int tt = 0; tt < 4; ++tt) {
        int col = colg[tt] - 128;      // 0..127
#pragma unroll
        for (int r = 0; r < 4; ++r) {
          int row = quad*4 + r;
          float gg = fast_sigmoid(ag[tt][r] + xg[tt][r] + bg[tt]);
          u_f[row][col] = gg;
        }
      }
    }
    __syncthreads();   // B1: rA / u visible

    // cand MFMA: acc[tt] covers cols w*32 + tt*16 (+l15)
    f32x4 ac[2] = {};
#pragma unroll
    for (int kt = 0; kt < 4; ++kt) {
      bf16x8 Ah = *(bf16x8*)&rAh[kt][l15][quad*8];
      bf16x8 Al = *(bf16x8*)&rAl[kt][l15][quad*8];
#pragma unroll
      for (int tt = 0; tt < 2; ++tt)
        ac[tt] = __builtin_amdgcn_mfma_f32_16x16x32_bf16(Ah, cBh[tt][kt], ac[tt], 0, 0, 0);
#pragma unroll
      for (int tt = 0; tt < 2; ++tt)
        ac[tt] = __builtin_amdgcn_mfma_f32_16x16x32_bf16(Ah, cBl[tt][kt], ac[tt], 0, 0, 0);
#pragma unroll
      for (int tt = 0; tt < 2; ++tt)
        ac[tt] = __builtin_amdgcn_mfma_f32_16x16x32_bf16(Al, cBh[tt][kt], ac[tt], 0, 0, 0);
    }

    // cand epilogue + h update (each (row,col) owned by exactly one lane)
#pragma unroll
    for (int tt = 0; tt < 2; ++tt) {
      int col = colc[tt];
      int kt2 = col >> 5, kk = col & 31;
#pragma unroll
      for (int r = 0; r < 4; ++r) {
        int row = quad*4 + r;
        float cs = ac[tt][r] + xc[tt][r] + bc[tt];
        float cd = fast_tanh(cs);
        float uu = u_f[row][col];
        float ho = h_f[row][col];
        float hn = uu * ho + (1.f - uu) * cd;
        if (t < Lr[r]) {
          h_f[row][col] = hn;
          unsigned short hi = f2bf_rne(hn);
          float hf = __uint_as_float((unsigned)hi << 16);
          hAh[kt2][row][kk] = (short)hi;
          hAl[kt2][row][kk] = (short)f2bf_rne(hn - hf);
          int pos = dir ? (Lr[r] - 1 - t) : t;
          stb[r][(size_t)pos * C_ + col] = hn;
        }
      }
    }
    __syncthreads();   // B2: h visible for next step

#pragma unroll
    for (int tt = 0; tt < 4; ++tt)
#pragma unroll
      for (int r = 0; r < 4; ++r) xg[tt][r] = xgn[tt][r];
#pragma unroll
    for (int tt = 0; tt < 2; ++tt)
#pragma unroll
      for (int r = 0; r < 4; ++r) xc[tt][r] = xcn[tt][r];
  }

  // zero states rows past each chain's L
  for (int i = 0; i < 16; ++i) {
    int b = b0 + i;
    int L = lenarr[b];
    float* sb = stroot + (size_t)b * S * C_;
    for (int idx = L * C_ + tid; idx < S * C_; idx += 256) sb[idx] = 0.f;
  }
}

// ---------------------------------------------------------------------------
// Attention v2 (standalone, proven): MFMA bf16x3 score projection, online
// softmax. Per WG one (b, dir, arr) chain.
// ---------------------------------------------------------------------------
__global__ __launch_bounds__(256, 2) void attn_kernel(
    const float* __restrict__ states, const short* __restrict__ awt_hi,
    const short* __restrict__ awt_lo, const float* __restrict__ att_v,
    const float* __restrict__ att_b, float* __restrict__ feats) {
  __shared__ __align__(16) float st_s[16][132];
  __shared__ __align__(16) short ah_s[16][132];
  __shared__ __align__(16) short al_s[16][132];
  __shared__ float spart[4][16];
  __shared__ float score_s[16];
  __shared__ float cm[128], cl[128], ca[128];

  int bid = blockIdx.x, tid = threadIdx.x;
  int b, dir, S, featOff; const float* stb;
  if (bid < 256) {
    b = bid >> 1; dir = bid & 1; S = SC_;
    stb = states + (dir ? SZ_ST_CTX : 0) + (size_t)b * SC_ * C_;
    featOff = dir * 128;
  } else {
    int q = bid - 256; b = q >> 1; dir = q & 1; S = SE_;
    stb = states + 2*SZ_ST_CTX + (dir ? SZ_ST_END : 0) + (size_t)b * SE_ * C_;
    featOff = 256 + dir * 128;
  }

  int w = tid >> 6, lane = tid & 63;
  int quad = lane >> 4, l15 = lane & 15;

  int d0 = 32 * w + l15, d1 = d0 + 16;
  bf16x8 bh0[4], bh1[4], bl0[4], bl1[4];
#pragma unroll
  for (int kt = 0; kt < 4; ++kt) {
    bh0[kt] = *(const bf16x8*)&awt_hi[d0*128 + kt*32 + quad*8];
    bh1[kt] = *(const bf16x8*)&awt_hi[d1*128 + kt*32 + quad*8];
    bl0[kt] = *(const bf16x8*)&awt_lo[d0*128 + kt*32 + quad*8];
    bl1[kt] = *(const bf16x8*)&awt_lo[d1*128 + kt*32 + quad*8];
  }
  float vv0 = att_v[d0], vv1 = att_v[d1];
  float bb0 = att_b[d0], bb1 = att_b[d1];

  int c = tid & 127, half = tid >> 7;
  float m = -1e30f, lsum = 0.f, acc = 0.f;

  int lrow = tid >> 4, lcol = (tid & 15) * 8;
  float4 p0, p1;
  {
    const float* src = stb + (size_t)lrow * C_ + lcol;
    p0 = *(const float4*)(src);
    p1 = *(const float4*)(src + 4);
  }

  int nchunks = S >> 4;
  for (int ch = 0; ch < nchunks; ++ch) {
    __syncthreads();   // B0
    float f[8] = {p0.x, p0.y, p0.z, p0.w, p1.x, p1.y, p1.z, p1.w};
    short hi8[8], lo8[8];
#pragma unroll
    for (int j = 0; j < 8; ++j) {
      unsigned short h = f2bf_rne(f[j]);
      float hf = __uint_as_float((unsigned)h << 16);
      hi8[j] = (short)h;
      lo8[j] = (short)f2bf_rne(f[j] - hf);
    }
    *(float4*)(&st_s[lrow][lcol])     = p0;
    *(float4*)(&st_s[lrow][lcol + 4]) = p1;
    *(bf16x8*)(&ah_s[lrow][lcol]) = *(bf16x8*)hi8;
    *(bf16x8*)(&al_s[lrow][lcol]) = *(bf16x8*)lo8;
    if (ch + 1 < nchunks) {
      const float* src = stb + (size_t)((ch + 1) * 16 + lrow) * C_ + lcol;
      p0 = *(const float4*)(src);
      p1 = *(const float4*)(src + 4);
    }
    __syncthreads();   // B1

    f32x4 ac0 = {0.f, 0.f, 0.f, 0.f}, ac1 = {0.f, 0.f, 0.f, 0.f};
#pragma unroll
    for (int kt = 0; kt < 4; ++kt) {
      bf16x8 a_hi = *(bf16x8*)&ah_s[l15][kt*32 + quad*8];
      bf16x8 a_lo = *(bf16x8*)&al_s[l15][kt*32 + quad*8];
      ac0 = __builtin_amdgcn_mfma_f32_16x16x32_bf16(a_hi, bh0[kt], ac0, 0, 0, 0);
      ac0 = __builtin_amdgcn_mfma_f32_16x16x32_bf16(a_hi, bl0[kt], ac0, 0, 0, 0);
      ac0 = __builtin_amdgcn_mfma_f32_16x16x32_bf16(a_lo, bh0[kt], ac0, 0, 0, 0);
      ac1 = __builtin_amdgcn_mfma_f32_16x16x32_bf16(a_hi, bh1[kt], ac1, 0, 0, 0);
      ac1 = __builtin_amdgcn_mfma_f32_16x16x32_bf16(a_hi, bl1[kt], ac1, 0, 0, 0);
      ac1 = __builtin_amdgcn_mfma_f32_16x16x32_bf16(a_lo, bh1[kt], ac1, 0, 0, 0);
    }

    float part[4];
#pragma unroll
    for (int r = 0; r < 4; ++r)
      part[r] = fast_tanh(ac0[r] + bb0) * vv0 + fast_tanh(ac1[r] + bb1) * vv1;
#pragma unroll
    for (int mask = 1; mask <= 8; mask <<= 1)
#pragma unroll
      for (int r = 0; r < 4; ++r)
        part[r] += __shfl_xor(part[r], mask, 64);
    if (l15 == 0) {
#pragma unroll
      for (int r = 0; r < 4; ++r) spart[w][quad*4 + r] = part[r];
    }
    __syncthreads();   // B2
    if (tid < 16)
      score_s[tid] = spart[0][tid] + spart[1][tid] + spart[2][tid] + spart[3][tid];
    __syncthreads();   // B3

    float srow[8]; float smax = m;
#pragma unroll
    for (int r = 0; r < 8; ++r) { srow[r] = score_s[half*8 + r]; smax = fmaxf(smax, srow[r]); }
    float scale = __expf(m - smax);
    acc *= scale; lsum *= scale; m = smax;
#pragma unroll
    for (int r = 0; r < 8; ++r) {
      float wgt = __expf(srow[r] - m);
      lsum += wgt;
      acc += wgt * st_s[half*8 + r][c];
    }
  }

  __syncthreads();
  if (half == 1) { cm[c] = m; cl[c] = lsum; ca[c] = acc; }
  __syncthreads();
  if (half == 0) {
    float m1 = cm[c], l1 = cl[c], a1 = ca[c];
    float M = fmaxf(m, m1);
    float w0 = __expf(m - M), w1 = __expf(m1 - M);
    feats[b * 512 + featOff + c] = (acc * w0 + a1 * w1) / (lsum * w0 + l1 * w1);
  }
}

// ---------------------------------------------------------------------------
// Head
// ---------------------------------------------------------------------------
__global__ __launch_bounds__(128) void head_kernel(
    const float* __restrict__ feats, const float* __restrict__ hid_w,
    const float* __restrict__ hid_b, const float* __restrict__ out_w,
    const float* __restrict__ out_b, float* __restrict__ out) {
  __shared__ __align__(16) float f_s[512];
  __shared__ float part[2];
  int b = blockIdx.x, tid = threadIdx.x;
  for (int i = tid; i < 512; i += 128) f_s[i] = feats[b * 512 + i];
  __syncthreads();
  float h = hid_b[tid];
  for (int k = 0; k < 512; ++k) h += f_s[k] * hid_w[k * 128 + tid];
  h = fmaxf(h, 0.f);
  float p = h * out_w[tid];
#pragma unroll
  for (int off = 32; off > 0; off >>= 1) p += __shfl_xor(p, off, 64);
  if ((tid & 63) == 0) part[tid >> 6] = p;
  __syncthreads();
  if (tid == 0) out[b] = part[0] + part[1] + out_b[0];
}

// ---------------------------------------------------------------------------
extern "C" void kernel_launch(void* const* d_in, const int* in_sizes, int n_in,
                              void* d_out, int out_size, void* d_ws, size_t ws_size,
                              hipStream_t stream) {
  const int*   ctx     = (const int*)d_in[0];
  const int*   endseq  = (const int*)d_in[1];
  const int*   ctx_len = (const int*)d_in[2];
  const int*   end_len = (const int*)d_in[3];
  const float* emb     = (const float*)d_in[4];
  const float* fw_gw   = (const float*)d_in[5];
  const float* fw_gb   = (const float*)d_in[6];
  const float* fw_cw   = (const float*)d_in[7];
  const float* fw_cb   = (const float*)d_in[8];
  const float* bw_gw   = (const float*)d_in[9];
  const float* bw_gb   = (const float*)d_in[10];
  const float* bw_cw   = (const float*)d_in[11];
  const float* bw_cb   = (const float*)d_in[12];
  const float* att_v   = (const float*)d_in[13];
  const float* att_w   = (const float*)d_in[14];
  const float* att_b   = (const float*)d_in[15];
  const float* hid_w   = (const float*)d_in[16];
  const float* hid_b   = (const float*)d_in[17];
  const float* out_w   = (const float*)d_in[18];
  const float* out_b   = (const float*)d_in[19];
  float* ws  = (float*)d_ws;
  float* out = (float*)d_out;

  short* Ahi    = (short*)(ws + OFF_ST);
  short* Alo    = Ahi + (size_t)V_ * KP;
  short* Bthi   = (short*)(ws + OFF_BT);
  short* Btlo   = Bthi + (size_t)NCOL * KP;
  short* awt_hi = (short*)(ws + OFF_AWT);
  short* awt_lo = awt_hi + 128 * 128;

  pack_kernel<<<1299, 256, 0, stream>>>(fw_gw, fw_gb, fw_cw, fw_cb,
                                        bw_gw, bw_gb, bw_cw, bw_cb, ws);
  pack_bt<<<(NCOL * KP + 128 * 128 + 255) / 256, 256, 0, stream>>>(
      ws + OFF_WXP, Bthi, Btlo, att_w, awt_hi, awt_lo);
  pack_emb<<<(int)(((size_t)V_ * KP + 255) / 256), 256, 0, stream>>>(emb, Ahi, Alo);

  gemm_mfma<<<2346, 256, 0, stream>>>(Ahi, Alo, Bthi, Btlo, ws + OFF_PROJ);

  recur_mfma_kernel<<<32, 256, 0, stream>>>(ctx, endseq, ctx_len, end_len,
                                            ws + OFF_PROJ, ws + OFF_UALL,
                                            ws + OFF_BIAS, ws + OFF_ST);

  attn_kernel<<<512, 256, 0, stream>>>(ws + OFF_ST, awt_hi, awt_lo,
                                       att_v, att_b, ws + OFF_FEATS);

  head_kernel<<<128, 128, 0, stream>>>(ws + OFF_FEATS, hid_w, hid_b,
                                       out_w, out_b, out);
}

// Round 6
// 809.053 us; speedup vs baseline: 2.5732x; 2.5732x over previous
//
#include <hip/hip_runtime.h>
#include <cstdint>
#include <cmath>

// Problem constants
static constexpr int V_  = 50000;
static constexpr int E_  = 300;
static constexpr int C_  = 128;
static constexpr int B_  = 128;
static constexpr int SC_ = 512;
static constexpr int SE_ = 64;
static constexpr int NCOL = 768;   // [fw_gate 256 | fw_cand 128 | bw_gate 256 | bw_cand 128]
static constexpr int KP  = 320;    // K padded to 10 x 32 for MFMA

// ws layout (float offsets)
static constexpr size_t OFF_PROJ  = 0;
static constexpr size_t SZ_PROJ   = (size_t)V_ * NCOL;
static constexpr size_t OFF_WXP   = OFF_PROJ + SZ_PROJ;
static constexpr size_t SZ_WXP    = (size_t)304 * NCOL;
static constexpr size_t OFF_UALL  = OFF_WXP + SZ_WXP;
static constexpr size_t SZ_UALL   = (size_t)C_ * NCOL;
static constexpr size_t OFF_BIAS  = OFF_UALL + SZ_UALL;
static constexpr size_t SZ_BIAS   = NCOL;
static constexpr size_t OFF_ST    = OFF_BIAS + SZ_BIAS;
static constexpr size_t SZ_ST_CTX = (size_t)B_ * SC_ * C_;
static constexpr size_t SZ_ST_END = (size_t)B_ * SE_ * C_;
static constexpr size_t SZ_ST     = 2*SZ_ST_CTX + 2*SZ_ST_END;    // 75.5 MB
static constexpr size_t OFF_FEATS = OFF_ST + SZ_ST;
static constexpr size_t SZ_FEATS  = (size_t)B_ * 512;
static constexpr size_t OFF_BT    = OFF_FEATS + SZ_FEATS;
static constexpr size_t SZ_BT     = (size_t)NCOL * KP / 2 * 2;    // 2 short arrays
static constexpr size_t OFF_AWT   = OFF_BT + SZ_BT;               // att_w^T hi/lo shorts
// A_hi/A_lo (bf16) OVERLAP the states region (dead once gemm ends; recur
// zeroes its own tail rows so no global memset is needed).

typedef __attribute__((ext_vector_type(8))) short bf16x8;
typedef __attribute__((ext_vector_type(4))) float f32x4;

static __device__ __forceinline__ unsigned short f2bf_rne(float f) {
  unsigned u = __float_as_uint(f);
  unsigned r = u + 0x7fffu + ((u >> 16) & 1u);
  return (unsigned short)(r >> 16);
}

static __device__ __forceinline__ void gload_lds16(const short* g, short* l) {
  __builtin_amdgcn_global_load_lds(
      (const __attribute__((address_space(1))) void*)g,
      (__attribute__((address_space(3))) void*)l, 16, 0, 0);
}

// LDS-only barrier: orders LDS producer->consumer WITHOUT the vmcnt(0) drain
// that __syncthreads() emits. Safe when (a) global stores before the barrier
// are never re-read in-kernel and (b) global loads are register-consumed
// (compiler tracks their vmcnt). sched_barrier(0) fences pin ordering
// (ERRATA #18: hipcc can hoist past inline-asm waitcnt).
static __device__ __forceinline__ void bar_lds() {
  __builtin_amdgcn_sched_barrier(0);
  asm volatile("s_waitcnt lgkmcnt(0)" ::: "memory");
  __builtin_amdgcn_s_barrier();
  __builtin_amdgcn_sched_barrier(0);
}

// fast activations: __expf + v_rcp_f32 (~1e-6 rel err; logit threshold 7.4e-5)
static __device__ __forceinline__ float fast_sigmoid(float x) {
  return __builtin_amdgcn_rcpf(1.f + __expf(-x));
}
static __device__ __forceinline__ float fast_tanh(float x) {
  return fmaf(-2.f, __builtin_amdgcn_rcpf(__expf(2.f * x) + 1.f), 1.f);
}

// ---------------------------------------------------------------------------
// Pack: Wxp[304][768] fp32, Uall[128][768], bias[768]
// ---------------------------------------------------------------------------
__global__ void pack_kernel(const float* __restrict__ fw_gw, const float* __restrict__ fw_gb,
                            const float* __restrict__ fw_cw, const float* __restrict__ fw_cb,
                            const float* __restrict__ bw_gw, const float* __restrict__ bw_gb,
                            const float* __restrict__ bw_cw, const float* __restrict__ bw_cb,
                            float* __restrict__ ws) {
  int i = blockIdx.x * 256 + threadIdx.x;
  float* Wxp  = ws + OFF_WXP;
  float* Uall = ws + OFF_UALL;
  float* bias = ws + OFF_BIAS;
  if (i < 304 * NCOL) {
    int k = i / NCOL, c = i % NCOL;
    float v = 0.f;
    if (k < 300) {
      if (c < 256)      v = fw_gw[k*256 + c];
      else if (c < 384) v = fw_cw[k*128 + (c-256)];
      else if (c < 640) v = bw_gw[k*256 + (c-384)];
      else              v = bw_cw[k*128 + (c-640)];
    }
    Wxp[i] = v;
    return;
  }
  int j = i - 304 * NCOL;
  if (j >= 0 && j < 128 * NCOL) {
    int k = j / NCOL, c = j % NCOL;
    int kk = 300 + k;
    float v;
    if (c < 256)      v = fw_gw[kk*256 + c];
    else if (c < 384) v = fw_cw[kk*128 + (c-256)];
    else if (c < 640) v = bw_gw[kk*256 + (c-384)];
    else              v = bw_cw[kk*128 + (c-640)];
    Uall[j] = v;
    return;
  }
  int m = j - 128 * NCOL;
  if (m >= 0 && m < NCOL) {
    float v;
    if (m < 256)      v = fw_gb[m];
    else if (m < 384) v = fw_cb[m-256];
    else if (m < 640) v = bw_gb[m-384];
    else              v = bw_cb[m-640];
    bias[m] = v;
  }
}

// Bt hi/lo for the proj GEMM + att_w^T hi/lo for the MFMA attention
__global__ void pack_bt(const float* __restrict__ Wxp, short* __restrict__ Bthi,
                        short* __restrict__ Btlo, const float* __restrict__ att_w,
                        short* __restrict__ awt_hi, short* __restrict__ awt_lo) {
  int i = blockIdx.x * 256 + threadIdx.x;
  if (i < NCOL * KP) {
    int k = i % KP, n = i / KP;
    float v = (k < 304) ? Wxp[(size_t)k * NCOL + n] : 0.f;
    unsigned short h = f2bf_rne(v);
    float hf = __uint_as_float((unsigned)h << 16);
    unsigned short lo = f2bf_rne(v - hf);
    Bthi[i] = (short)h;
    Btlo[i] = (short)lo;
    return;
  }
  int j = i - NCOL * KP;
  if (j < 128 * 128) {
    int d = j >> 7, c = j & 127;
    float v = att_w[(size_t)c * 128 + d];   // transpose: awt[d][k=c]
    unsigned short h = f2bf_rne(v);
    float hf = __uint_as_float((unsigned)h << 16);
    unsigned short lo = f2bf_rne(v - hf);
    awt_hi[j] = (short)h;
    awt_lo[j] = (short)lo;
  }
}

__global__ void pack_emb(const float* __restrict__ emb, short* __restrict__ Ahi,
                         short* __restrict__ Alo) {
  size_t i = (size_t)blockIdx.x * 256 + threadIdx.x;
  if (i >= (size_t)V_ * KP) return;
  int k = (int)(i % KP);
  size_t row = i / KP;
  float v = (k < E_) ? emb[row * E_ + k] : 0.f;
  unsigned short h = f2bf_rne(v);
  float hf = __uint_as_float((unsigned)h << 16);
  unsigned short lo = f2bf_rne(v - hf);
  Ahi[i] = (short)h;
  Alo[i] = (short)lo;
}

// ---------------------------------------------------------------------------
// proj = emb @ Wxp via bf16x3 split MFMA (m97 structure). Linear grid +
// bijective XCD swizzle (m204): all 6 n-blocks of one m-tile on one XCD.
// ---------------------------------------------------------------------------
__global__ __launch_bounds__(256) void gemm_mfma(
    const short* __restrict__ Ahi, const short* __restrict__ Alo,
    const short* __restrict__ Bthi, const short* __restrict__ Btlo,
    float* __restrict__ proj) {
  __shared__ short lds[16384];
  int tid = threadIdx.x, wid = tid >> 6, lane = tid & 63;

  // bijective XCD swizzle: nwg=2346, q=293, r=2
  int bid = blockIdx.x;
  int xcd = bid & 7, idx = bid >> 3;
  int wgid = (xcd < 2 ? xcd * 294 : 588 + (xcd - 2) * 293) + idx;
  int m0 = (wgid / 6) * 128;
  int n0 = (wgid % 6) * 128;

  f32x4 acc[4][4] = {};

  int lr = lane >> 2, lc = lane & 3;
  int q0 = wid * 2, q1 = q0 + 1;
  int r0 = q0 * 16 + lr, r1 = q1 * 16 + lr;
  int am0 = m0 + r0; if (am0 > V_ - 1) am0 = V_ - 1;
  int am1 = m0 + r1; if (am1 > V_ - 1) am1 = V_ - 1;
  size_t gaOff0 = (size_t)am0 * KP + lc * 8;
  size_t gaOff1 = (size_t)am1 * KP + lc * 8;
  size_t gbOff0 = (size_t)(n0 + r0) * KP + lc * 8;
  size_t gbOff1 = (size_t)(n0 + r1) * KP + lc * 8;

  int quad = lane >> 4;
  int arow = (wid >> 1) * 64 + (lane & 15);
  int brow = (wid & 1) * 64 + (lane & 15);

  for (int k0 = 0; k0 < KP; k0 += 32) {
    gload_lds16(Ahi  + gaOff0 + k0, lds +         q0 * 512);
    gload_lds16(Ahi  + gaOff1 + k0, lds +         q1 * 512);
    gload_lds16(Alo  + gaOff0 + k0, lds +  4096 + q0 * 512);
    gload_lds16(Alo  + gaOff1 + k0, lds +  4096 + q1 * 512);
    gload_lds16(Bthi + gbOff0 + k0, lds +  8192 + q0 * 512);
    gload_lds16(Bthi + gbOff1 + k0, lds +  8192 + q1 * 512);
    gload_lds16(Btlo + gbOff0 + k0, lds + 12288 + q0 * 512);
    gload_lds16(Btlo + gbOff1 + k0, lds + 12288 + q1 * 512);
    __syncthreads();

    bf16x8 ah[4], al[4], bh[4], bl[4];
#pragma unroll
    for (int i = 0; i < 4; ++i) {
      ah[i] = *(bf16x8*)&lds[        (arow + i*16) * 32 + quad * 8];
      al[i] = *(bf16x8*)&lds[ 4096 + (arow + i*16) * 32 + quad * 8];
      bh[i] = *(bf16x8*)&lds[ 8192 + (brow + i*16) * 32 + quad * 8];
      bl[i] = *(bf16x8*)&lds[12288 + (brow + i*16) * 32 + quad * 8];
    }
#pragma unroll
    for (int i = 0; i < 4; ++i)
#pragma unroll
      for (int j = 0; j < 4; ++j) {
        acc[i][j] = __builtin_amdgcn_mfma_f32_16x16x32_bf16(ah[i], bh[j], acc[i][j], 0, 0, 0);
        acc[i][j] = __builtin_amdgcn_mfma_f32_16x16x32_bf16(ah[i], bl[j], acc[i][j], 0, 0, 0);
        acc[i][j] = __builtin_amdgcn_mfma_f32_16x16x32_bf16(al[i], bh[j], acc[i][j], 0, 0, 0);
      }
    __syncthreads();
  }

  int colb = n0 + (wid & 1) * 64 + (lane & 15);
  int rowb = m0 + (wid >> 1) * 64 + quad * 4;
#pragma unroll
  for (int i = 0; i < 4; ++i) {
    int rb = rowb + i * 16;
#pragma unroll
    for (int j = 0; j < 4; ++j) {
      int cc = colb + j * 16;
#pragma unroll
      for (int r = 0; r < 4; ++r) {
        int rr = rb + r;
        if (rr < V_) proj[(size_t)rr * NCOL + cc] = acc[i][j][r];
      }
    }
  }
}

// ---------------------------------------------------------------------------
// Recurrence (round-0 body, 466us proven) + two latency fixes:
//  (1) bar_lds() instead of __syncthreads(): no vmcnt(0) drain per barrier,
//      so the x-row prefetch spans the full step and the h-state stores are
//      never waited on.
//  (2) 2-step-ahead TOKEN prefetch: the token->x-row dependent-load chain is
//      split across two steps (token for t+2 loads during step t; x rows for
//      t+1 are issued with the token already in-register).
// ---------------------------------------------------------------------------
__global__ __attribute__((amdgpu_flat_work_group_size(256, 256),
                          amdgpu_waves_per_eu(2, 2)))
void recur_kernel(
    const int* __restrict__ ctx, const int* __restrict__ endseq,
    const int* __restrict__ ctx_len, const int* __restrict__ end_len,
    const float* __restrict__ proj, const float* __restrict__ Uall,
    const float* __restrict__ bias, float* __restrict__ states) {
  __shared__ __align__(16) float h_s[128];
  __shared__ __align__(16) float rh_s[128];
  __shared__ __align__(16) float u_s[128];
  __shared__ __align__(16) float pg[8][260];
  __shared__ __align__(16) float pc[8][132];

  int bid = blockIdx.x;
  int tid = threadIdx.x;
  const int* seq; int S, L, b, dir; float* stbase;
  if (bid < 256) {
    b = bid >> 1; dir = bid & 1;
    seq = ctx + b * SC_; S = SC_; L = ctx_len[b];
    stbase = states + (dir ? SZ_ST_CTX : 0) + (size_t)b * SC_ * C_;
  } else {
    int q = bid - 256; b = q >> 1; dir = q & 1;
    seq = endseq + b * SE_; S = SE_; L = end_len[b];
    stbase = states + 2*SZ_ST_CTX + (dir ? SZ_ST_END : 0) + (size_t)b * SE_ * C_;
  }
  int dirOff = dir ? 384 : 0;
  int kg = tid >> 5, jg = tid & 31;

  float wg[16][8];
  float wc[16][4];
#pragma unroll
  for (int kk = 0; kk < 16; ++kk) {
    const float* up = Uall + (size_t)(kg*16 + kk) * NCOL + dirOff;
    float4 w0 = *(const float4*)(up + jg*8);
    float4 w1 = *(const float4*)(up + jg*8 + 4);
    wg[kk][0]=w0.x; wg[kk][1]=w0.y; wg[kk][2]=w0.z; wg[kk][3]=w0.w;
    wg[kk][4]=w1.x; wg[kk][5]=w1.y; wg[kk][6]=w1.z; wg[kk][7]=w1.w;
    float4 wv = *(const float4*)(up + 256 + jg*4);
    wc[kk][0]=wv.x; wc[kk][1]=wv.y; wc[kk][2]=wv.z; wc[kk][3]=wv.w;
  }
  float bias_g = bias[dirOff + tid];
  float bias_c = (tid < 128) ? bias[dirOff + 256 + tid] : 0.f;

  if (tid < 128) h_s[tid] = 0.f;
  __syncthreads();

  // t=0 x row (blocking) + token for t=1 (in-register by the time step 0 ends)
  int pos0 = dir ? (L - 1) : 0;
  int tok0 = seq[pos0];
  const float* xr0 = proj + (size_t)tok0 * NCOL + dirOff;
  float xg = xr0[tid];
  float xc = (tid < 128) ? xr0[256 + tid] : 0.f;
  int tok_nx = 0;
  if (L > 1) tok_nx = seq[dir ? (L - 2) : 1];

  for (int t = 0; t < L; ++t) {
    // issue x prefetch for t+1 (token already resident -> no dependent chain)
    float xg_n = 0.f, xc_n = 0.f;
    if (t + 1 < L) {
      const float* xr = proj + (size_t)tok_nx * NCOL + dirOff;
      xg_n = xr[tid];
      xc_n = (tid < 128) ? xr[256 + tid] : 0.f;
    }
    // token prefetch for t+2 (completes during this step)
    int tok_n2 = 0;
    if (t + 2 < L) tok_n2 = seq[dir ? (L - 3 - t) : (t + 2)];

    float a[8] = {0.f,0.f,0.f,0.f,0.f,0.f,0.f,0.f};
    const float4* h4 = (const float4*)h_s;
#pragma unroll
    for (int q = 0; q < 4; ++q) {
      float4 hv = h4[kg*4 + q];
      float he[4] = {hv.x, hv.y, hv.z, hv.w};
#pragma unroll
      for (int e = 0; e < 4; ++e)
#pragma unroll
        for (int jj = 0; jj < 8; ++jj)
          a[jj] += he[e] * wg[q*4 + e][jj];
    }
    *(float4*)(&pg[kg][jg*8])     = make_float4(a[0], a[1], a[2], a[3]);
    *(float4*)(&pg[kg][jg*8 + 4]) = make_float4(a[4], a[5], a[6], a[7]);
    bar_lds();   // B1

    float g = xg + bias_g;
#pragma unroll
    for (int k2 = 0; k2 < 8; ++k2) g += pg[k2][tid];
    g = fast_sigmoid(g);

    float h_old = 0.f;
    if (tid < 128) { h_old = h_s[tid]; rh_s[tid] = g * h_old; }
    else           { u_s[tid - 128] = g; }
    bar_lds();   // B2

    float ac[4] = {0.f, 0.f, 0.f, 0.f};
    const float4* rh4 = (const float4*)rh_s;
#pragma unroll
    for (int q = 0; q < 4; ++q) {
      float4 rv = rh4[kg*4 + q];
      float re[4] = {rv.x, rv.y, rv.z, rv.w};
#pragma unroll
      for (int e = 0; e < 4; ++e)
#pragma unroll
        for (int jj = 0; jj < 4; ++jj)
          ac[jj] += re[e] * wc[q*4 + e][jj];
    }
    *(float4*)(&pc[kg][jg*4]) = make_float4(ac[0], ac[1], ac[2], ac[3]);
    bar_lds();   // B3

    if (tid < 128) {
      float cs = xc + bias_c;
#pragma unroll
      for (int k2 = 0; k2 < 8; ++k2) cs += pc[k2][tid];
      float c = fast_tanh(cs);
      float u = u_s[tid];
      float hn = u * h_old + (1.f - u) * c;
      h_s[tid] = hn;
      int pos = dir ? (L - 1 - t) : t;
      stbase[(size_t)pos * C_ + tid] = hn;   // never re-read in-kernel
    }
    bar_lds();   // B4
    xg = xg_n; xc = xc_n; tok_nx = tok_n2;
  }

  for (int i = L * C_ + tid; i < S * C_; i += 256) stbase[i] = 0.f;
}

// ---------------------------------------------------------------------------
// Attention (proven structure) with bar_lds(): the chunk prefetch loads are
// no longer drained at the staging barriers, so they genuinely overlap the
// MFMA + softmax of the previous chunk.
// ---------------------------------------------------------------------------
__global__ __launch_bounds__(256, 2) void attn_kernel(
    const float* __restrict__ states, const short* __restrict__ awt_hi,
    const short* __restrict__ awt_lo, const float* __restrict__ att_v,
    const float* __restrict__ att_b, float* __restrict__ feats) {
  __shared__ __align__(16) float st_s[16][132];
  __shared__ __align__(16) short ah_s[16][132];
  __shared__ __align__(16) short al_s[16][132];
  __shared__ float spart[4][16];
  __shared__ float score_s[16];
  __shared__ float cm[128], cl[128], ca[128];

  int bid = blockIdx.x, tid = threadIdx.x;
  int b, dir, S, featOff; const float* stb;
  if (bid < 256) {
    b = bid >> 1; dir = bid & 1; S = SC_;
    stb = states + (dir ? SZ_ST_CTX : 0) + (size_t)b * SC_ * C_;
    featOff = dir * 128;
  } else {
    int q = bid - 256; b = q >> 1; dir = q & 1; S = SE_;
    stb = states + 2*SZ_ST_CTX + (dir ? SZ_ST_END : 0) + (size_t)b * SE_ * C_;
    featOff = 256 + dir * 128;
  }

  int w = tid >> 6, lane = tid & 63;
  int quad = lane >> 4, l15 = lane & 15;

  int d0 = 32 * w + l15, d1 = d0 + 16;
  bf16x8 bh0[4], bh1[4], bl0[4], bl1[4];
#pragma unroll
  for (int kt = 0; kt < 4; ++kt) {
    bh0[kt] = *(const bf16x8*)&awt_hi[d0*128 + kt*32 + quad*8];
    bh1[kt] = *(const bf16x8*)&awt_hi[d1*128 + kt*32 + quad*8];
    bl0[kt] = *(const bf16x8*)&awt_lo[d0*128 + kt*32 + quad*8];
    bl1[kt] = *(const bf16x8*)&awt_lo[d1*128 + kt*32 + quad*8];
  }
  float vv0 = att_v[d0], vv1 = att_v[d1];
  float bb0 = att_b[d0], bb1 = att_b[d1];

  int c = tid & 127, half = tid >> 7;
  float m = -1e30f, lsum = 0.f, acc = 0.f;

  int lrow = tid >> 4, lcol = (tid & 15) * 8;
  float4 p0, p1;
  {
    const float* src = stb + (size_t)lrow * C_ + lcol;
    p0 = *(const float4*)(src);
    p1 = *(const float4*)(src + 4);
  }

  int nchunks = S >> 4;
  for (int ch = 0; ch < nchunks; ++ch) {
    bar_lds();   // B0: prior chunk's LDS readers done
    float f[8] = {p0.x, p0.y, p0.z, p0.w, p1.x, p1.y, p1.z, p1.w};
    short hi8[8], lo8[8];
#pragma unroll
    for (int j = 0; j < 8; ++j) {
      unsigned short h = f2bf_rne(f[j]);
      float hf = __uint_as_float((unsigned)h << 16);
      hi8[j] = (short)h;
      lo8[j] = (short)f2bf_rne(f[j] - hf);
    }
    *(float4*)(&st_s[lrow][lcol])     = p0;
    *(float4*)(&st_s[lrow][lcol + 4]) = p1;
    *(bf16x8*)(&ah_s[lrow][lcol]) = *(bf16x8*)hi8;
    *(bf16x8*)(&al_s[lrow][lcol]) = *(bf16x8*)lo8;
    if (ch + 1 < nchunks) {   // prefetch next chunk (now truly in flight)
      const float* src = stb + (size_t)((ch + 1) * 16 + lrow) * C_ + lcol;
      p0 = *(const float4*)(src);
      p1 = *(const float4*)(src + 4);
    }
    bar_lds();   // B1: staging visible

    f32x4 ac0 = {0.f, 0.f, 0.f, 0.f}, ac1 = {0.f, 0.f, 0.f, 0.f};
#pragma unroll
    for (int kt = 0; kt < 4; ++kt) {
      bf16x8 a_hi = *(bf16x8*)&ah_s[l15][kt*32 + quad*8];
      bf16x8 a_lo = *(bf16x8*)&al_s[l15][kt*32 + quad*8];
      ac0 = __builtin_amdgcn_mfma_f32_16x16x32_bf16(a_hi, bh0[kt], ac0, 0, 0, 0);
      ac0 = __builtin_amdgcn_mfma_f32_16x16x32_bf16(a_hi, bl0[kt], ac0, 0, 0, 0);
      ac0 = __builtin_amdgcn_mfma_f32_16x16x32_bf16(a_lo, bh0[kt], ac0, 0, 0, 0);
      ac1 = __builtin_amdgcn_mfma_f32_16x16x32_bf16(a_hi, bh1[kt], ac1, 0, 0, 0);
      ac1 = __builtin_amdgcn_mfma_f32_16x16x32_bf16(a_hi, bl1[kt], ac1, 0, 0, 0);
      ac1 = __builtin_amdgcn_mfma_f32_16x16x32_bf16(a_lo, bh1[kt], ac1, 0, 0, 0);
    }

    float part[4];
#pragma unroll
    for (int r = 0; r < 4; ++r)
      part[r] = fast_tanh(ac0[r] + bb0) * vv0 + fast_tanh(ac1[r] + bb1) * vv1;
#pragma unroll
    for (int mask = 1; mask <= 8; mask <<= 1)
#pragma unroll
      for (int r = 0; r < 4; ++r)
        part[r] += __shfl_xor(part[r], mask, 64);
    if (l15 == 0) {
#pragma unroll
      for (int r = 0; r < 4; ++r) spart[w][quad*4 + r] = part[r];
    }
    bar_lds();   // B2: spart visible
    if (tid < 16)
      score_s[tid] = spart[0][tid] + spart[1][tid] + spart[2][tid] + spart[3][tid];
    bar_lds();   // B3: scores visible

    float srow[8]; float smax = m;
#pragma unroll
    for (int r = 0; r < 8; ++r) { srow[r] = score_s[half*8 + r]; smax = fmaxf(smax, srow[r]); }
    float scale = __expf(m - smax);
    acc *= scale; lsum *= scale; m = smax;
#pragma unroll
    for (int r = 0; r < 8; ++r) {
      float wgt = __expf(srow[r] - m);
      lsum += wgt;
      acc += wgt * st_s[half*8 + r][c];
    }
  }

  bar_lds();
  if (half == 1) { cm[c] = m; cl[c] = lsum; ca[c] = acc; }
  bar_lds();
  if (half == 0) {
    float m1 = cm[c], l1 = cl[c], a1 = ca[c];
    float M = fmaxf(m, m1);
    float w0 = __expf(m - M), w1 = __expf(m1 - M);
    feats[b * 512 + featOff + c] = (acc * w0 + a1 * w1) / (lsum * w0 + l1 * w1);
  }
}

// ---------------------------------------------------------------------------
// Head
// ---------------------------------------------------------------------------
__global__ __launch_bounds__(128) void head_kernel(
    const float* __restrict__ feats, const float* __restrict__ hid_w,
    const float* __restrict__ hid_b, const float* __restrict__ out_w,
    const float* __restrict__ out_b, float* __restrict__ out) {
  __shared__ __align__(16) float f_s[512];
  __shared__ float part[2];
  int b = blockIdx.x, tid = threadIdx.x;
  for (int i = tid; i < 512; i += 128) f_s[i] = feats[b * 512 + i];
  __syncthreads();
  float h = hid_b[tid];
  for (int k = 0; k < 512; ++k) h += f_s[k] * hid_w[k * 128 + tid];
  h = fmaxf(h, 0.f);
  float p = h * out_w[tid];
#pragma unroll
  for (int off = 32; off > 0; off >>= 1) p += __shfl_xor(p, off, 64);
  if ((tid & 63) == 0) part[tid >> 6] = p;
  __syncthreads();
  if (tid == 0) out[b] = part[0] + part[1] + out_b[0];
}

// ---------------------------------------------------------------------------
extern "C" void kernel_launch(void* const* d_in, const int* in_sizes, int n_in,
                              void* d_out, int out_size, void* d_ws, size_t ws_size,
                              hipStream_t stream) {
  const int*   ctx     = (const int*)d_in[0];
  const int*   endseq  = (const int*)d_in[1];
  const int*   ctx_len = (const int*)d_in[2];
  const int*   end_len = (const int*)d_in[3];
  const float* emb     = (const float*)d_in[4];
  const float* fw_gw   = (const float*)d_in[5];
  const float* fw_gb   = (const float*)d_in[6];
  const float* fw_cw   = (const float*)d_in[7];
  const float* fw_cb   = (const float*)d_in[8];
  const float* bw_gw   = (const float*)d_in[9];
  const float* bw_gb   = (const float*)d_in[10];
  const float* bw_cw   = (const float*)d_in[11];
  const float* bw_cb   = (const float*)d_in[12];
  const float* att_v   = (const float*)d_in[13];
  const float* att_w   = (const float*)d_in[14];
  const float* att_b   = (const float*)d_in[15];
  const float* hid_w   = (const float*)d_in[16];
  const float* hid_b   = (const float*)d_in[17];
  const float* out_w   = (const float*)d_in[18];
  const float* out_b   = (const float*)d_in[19];
  float* ws  = (float*)d_ws;
  float* out = (float*)d_out;

  short* Ahi    = (short*)(ws + OFF_ST);
  short* Alo    = Ahi + (size_t)V_ * KP;
  short* Bthi   = (short*)(ws + OFF_BT);
  short* Btlo   = Bthi + (size_t)NCOL * KP;
  short* awt_hi = (short*)(ws + OFF_AWT);
  short* awt_lo = awt_hi + 128 * 128;

  pack_kernel<<<1299, 256, 0, stream>>>(fw_gw, fw_gb, fw_cw, fw_cb,
                                        bw_gw, bw_gb, bw_cw, bw_cb, ws);
  pack_bt<<<(NCOL * KP + 128 * 128 + 255) / 256, 256, 0, stream>>>(
      ws + OFF_WXP, Bthi, Btlo, att_w, awt_hi, awt_lo);
  pack_emb<<<(int)(((size_t)V_ * KP + 255) / 256), 256, 0, stream>>>(emb, Ahi, Alo);

  gemm_mfma<<<2346, 256, 0, stream>>>(Ahi, Alo, Bthi, Btlo, ws + OFF_PROJ);

  recur_kernel<<<512, 256, 0, stream>>>(ctx, endseq, ctx_len, end_len,
                                        ws + OFF_PROJ, ws + OFF_UALL,
                                        ws + OFF_BIAS, ws + OFF_ST);

  attn_kernel<<<512, 256, 0, stream>>>(ws + OFF_ST, awt_hi, awt_lo,
                                       att_v, att_b, ws + OFF_FEATS);

  head_kernel<<<128, 128, 0, stream>>>(ws + OFF_FEATS, hid_w, hid_b,
                                       out_w, out_b, out);
}

// Round 7
// 770.322 us; speedup vs baseline: 2.7026x; 1.0503x over previous
//
#include <hip/hip_runtime.h>
#include <cstdint>
#include <cmath>

// Problem constants
static constexpr int V_  = 50000;
static constexpr int E_  = 300;
static constexpr int C_  = 128;
static constexpr int B_  = 128;
static constexpr int SC_ = 512;
static constexpr int SE_ = 64;
static constexpr int NCOL = 768;   // [fw_gate 256 | fw_cand 128 | bw_gate 256 | bw_cand 128]
static constexpr int KP  = 320;    // K padded to 10 x 32 for MFMA

// ws layout (float offsets)
static constexpr size_t OFF_PROJ  = 0;
static constexpr size_t SZ_PROJ   = (size_t)V_ * NCOL;
static constexpr size_t OFF_WXP   = OFF_PROJ + SZ_PROJ;
static constexpr size_t SZ_WXP    = (size_t)304 * NCOL;
static constexpr size_t OFF_UALL  = OFF_WXP + SZ_WXP;
static constexpr size_t SZ_UALL   = (size_t)C_ * NCOL;
static constexpr size_t OFF_BIAS  = OFF_UALL + SZ_UALL;
static constexpr size_t SZ_BIAS   = NCOL;
static constexpr size_t OFF_ST    = OFF_BIAS + SZ_BIAS;
static constexpr size_t SZ_ST_CTX = (size_t)B_ * SC_ * C_;
static constexpr size_t SZ_ST_END = (size_t)B_ * SE_ * C_;
static constexpr size_t SZ_ST     = 2*SZ_ST_CTX + 2*SZ_ST_END;    // 75.5 MB
static constexpr size_t OFF_FEATS = OFF_ST + SZ_ST;
static constexpr size_t SZ_FEATS  = (size_t)B_ * 512;
static constexpr size_t OFF_BT    = OFF_FEATS + SZ_FEATS;
static constexpr size_t SZ_BT     = (size_t)NCOL * KP / 2 * 2;    // 2 short arrays
static constexpr size_t OFF_AWT   = OFF_BT + SZ_BT;               // att_w^T hi/lo shorts
// A_hi/A_lo (bf16) OVERLAP the states region (dead once gemm ends; recur
// zeroes its own tail rows so no global memset is needed).

typedef __attribute__((ext_vector_type(8))) short bf16x8;
typedef __attribute__((ext_vector_type(4))) float f32x4;

static __device__ __forceinline__ unsigned short f2bf_rne(float f) {
  unsigned u = __float_as_uint(f);
  unsigned r = u + 0x7fffu + ((u >> 16) & 1u);
  return (unsigned short)(r >> 16);
}

static __device__ __forceinline__ void gload_lds16(const short* g, short* l) {
  __builtin_amdgcn_global_load_lds(
      (const __attribute__((address_space(1))) void*)g,
      (__attribute__((address_space(3))) void*)l, 16, 0, 0);
}

// fast activations: __expf + v_rcp_f32 (~1e-6 rel err; logit threshold 7.4e-5)
static __device__ __forceinline__ float fast_sigmoid(float x) {
  return __builtin_amdgcn_rcpf(1.f + __expf(-x));
}
static __device__ __forceinline__ float fast_tanh(float x) {
  return fmaf(-2.f, __builtin_amdgcn_rcpf(__expf(2.f * x) + 1.f), 1.f);
}

// ---------------------------------------------------------------------------
// Pack: Wxp[304][768] fp32, Uall[128][768], bias[768]
// ---------------------------------------------------------------------------
__global__ void pack_kernel(const float* __restrict__ fw_gw, const float* __restrict__ fw_gb,
                            const float* __restrict__ fw_cw, const float* __restrict__ fw_cb,
                            const float* __restrict__ bw_gw, const float* __restrict__ bw_gb,
                            const float* __restrict__ bw_cw, const float* __restrict__ bw_cb,
                            float* __restrict__ ws) {
  int i = blockIdx.x * 256 + threadIdx.x;
  float* Wxp  = ws + OFF_WXP;
  float* Uall = ws + OFF_UALL;
  float* bias = ws + OFF_BIAS;
  if (i < 304 * NCOL) {
    int k = i / NCOL, c = i % NCOL;
    float v = 0.f;
    if (k < 300) {
      if (c < 256)      v = fw_gw[k*256 + c];
      else if (c < 384) v = fw_cw[k*128 + (c-256)];
      else if (c < 640) v = bw_gw[k*256 + (c-384)];
      else              v = bw_cw[k*128 + (c-640)];
    }
    Wxp[i] = v;
    return;
  }
  int j = i - 304 * NCOL;
  if (j >= 0 && j < 128 * NCOL) {
    int k = j / NCOL, c = j % NCOL;
    int kk = 300 + k;
    float v;
    if (c < 256)      v = fw_gw[kk*256 + c];
    else if (c < 384) v = fw_cw[kk*128 + (c-256)];
    else if (c < 640) v = bw_gw[kk*256 + (c-384)];
    else              v = bw_cw[kk*128 + (c-640)];
    Uall[j] = v;
    return;
  }
  int m = j - 128 * NCOL;
  if (m >= 0 && m < NCOL) {
    float v;
    if (m < 256)      v = fw_gb[m];
    else if (m < 384) v = fw_cb[m-256];
    else if (m < 640) v = bw_gb[m-384];
    else              v = bw_cb[m-640];
    bias[m] = v;
  }
}

// Bt hi/lo for the proj GEMM + att_w^T hi/lo for the MFMA attention
__global__ void pack_bt(const float* __restrict__ Wxp, short* __restrict__ Bthi,
                        short* __restrict__ Btlo, const float* __restrict__ att_w,
                        short* __restrict__ awt_hi, short* __restrict__ awt_lo) {
  int i = blockIdx.x * 256 + threadIdx.x;
  if (i < NCOL * KP) {
    int k = i % KP, n = i / KP;
    float v = (k < 304) ? Wxp[(size_t)k * NCOL + n] : 0.f;
    unsigned short h = f2bf_rne(v);
    float hf = __uint_as_float((unsigned)h << 16);
    unsigned short lo = f2bf_rne(v - hf);
    Bthi[i] = (short)h;
    Btlo[i] = (short)lo;
    return;
  }
  int j = i - NCOL * KP;
  if (j < 128 * 128) {
    int d = j >> 7, c = j & 127;
    float v = att_w[(size_t)c * 128 + d];   // transpose: awt[d][k=c]
    unsigned short h = f2bf_rne(v);
    float hf = __uint_as_float((unsigned)h << 16);
    unsigned short lo = f2bf_rne(v - hf);
    awt_hi[j] = (short)h;
    awt_lo[j] = (short)lo;
  }
}

__global__ void pack_emb(const float* __restrict__ emb, short* __restrict__ Ahi,
                         short* __restrict__ Alo) {
  size_t i = (size_t)blockIdx.x * 256 + threadIdx.x;
  if (i >= (size_t)V_ * KP) return;
  int k = (int)(i % KP);
  size_t row = i / KP;
  float v = (k < E_) ? emb[row * E_ + k] : 0.f;
  unsigned short h = f2bf_rne(v);
  float hf = __uint_as_float((unsigned)h << 16);
  unsigned short lo = f2bf_rne(v - hf);
  Ahi[i] = (short)h;
  Alo[i] = (short)lo;
}

// ---------------------------------------------------------------------------
// proj = emb @ Wxp via bf16x3 split MFMA (m97 structure). Linear grid +
// bijective XCD swizzle (m204): all 6 n-blocks of one m-tile on one XCD.
// ---------------------------------------------------------------------------
__global__ __launch_bounds__(256) void gemm_mfma(
    const short* __restrict__ Ahi, const short* __restrict__ Alo,
    const short* __restrict__ Bthi, const short* __restrict__ Btlo,
    float* __restrict__ proj) {
  __shared__ short lds[16384];
  int tid = threadIdx.x, wid = tid >> 6, lane = tid & 63;

  // bijective XCD swizzle: nwg=2346, q=293, r=2
  int bid = blockIdx.x;
  int xcd = bid & 7, idx = bid >> 3;
  int wgid = (xcd < 2 ? xcd * 294 : 588 + (xcd - 2) * 293) + idx;
  int m0 = (wgid / 6) * 128;
  int n0 = (wgid % 6) * 128;

  f32x4 acc[4][4] = {};

  int lr = lane >> 2, lc = lane & 3;
  int q0 = wid * 2, q1 = q0 + 1;
  int r0 = q0 * 16 + lr, r1 = q1 * 16 + lr;
  int am0 = m0 + r0; if (am0 > V_ - 1) am0 = V_ - 1;
  int am1 = m0 + r1; if (am1 > V_ - 1) am1 = V_ - 1;
  size_t gaOff0 = (size_t)am0 * KP + lc * 8;
  size_t gaOff1 = (size_t)am1 * KP + lc * 8;
  size_t gbOff0 = (size_t)(n0 + r0) * KP + lc * 8;
  size_t gbOff1 = (size_t)(n0 + r1) * KP + lc * 8;

  int quad = lane >> 4;
  int arow = (wid >> 1) * 64 + (lane & 15);
  int brow = (wid & 1) * 64 + (lane & 15);

  for (int k0 = 0; k0 < KP; k0 += 32) {
    gload_lds16(Ahi  + gaOff0 + k0, lds +         q0 * 512);
    gload_lds16(Ahi  + gaOff1 + k0, lds +         q1 * 512);
    gload_lds16(Alo  + gaOff0 + k0, lds +  4096 + q0 * 512);
    gload_lds16(Alo  + gaOff1 + k0, lds +  4096 + q1 * 512);
    gload_lds16(Bthi + gbOff0 + k0, lds +  8192 + q0 * 512);
    gload_lds16(Bthi + gbOff1 + k0, lds +  8192 + q1 * 512);
    gload_lds16(Btlo + gbOff0 + k0, lds + 12288 + q0 * 512);
    gload_lds16(Btlo + gbOff1 + k0, lds + 12288 + q1 * 512);
    __syncthreads();

    bf16x8 ah[4], al[4], bh[4], bl[4];
#pragma unroll
    for (int i = 0; i < 4; ++i) {
      ah[i] = *(bf16x8*)&lds[        (arow + i*16) * 32 + quad * 8];
      al[i] = *(bf16x8*)&lds[ 4096 + (arow + i*16) * 32 + quad * 8];
      bh[i] = *(bf16x8*)&lds[ 8192 + (brow + i*16) * 32 + quad * 8];
      bl[i] = *(bf16x8*)&lds[12288 + (brow + i*16) * 32 + quad * 8];
    }
#pragma unroll
    for (int i = 0; i < 4; ++i)
#pragma unroll
      for (int j = 0; j < 4; ++j) {
        acc[i][j] = __builtin_amdgcn_mfma_f32_16x16x32_bf16(ah[i], bh[j], acc[i][j], 0, 0, 0);
        acc[i][j] = __builtin_amdgcn_mfma_f32_16x16x32_bf16(ah[i], bl[j], acc[i][j], 0, 0, 0);
        acc[i][j] = __builtin_amdgcn_mfma_f32_16x16x32_bf16(al[i], bh[j], acc[i][j], 0, 0, 0);
      }
    __syncthreads();
  }

  int colb = n0 + (wid & 1) * 64 + (lane & 15);
  int rowb = m0 + (wid >> 1) * 64 + quad * 4;
#pragma unroll
  for (int i = 0; i < 4; ++i) {
    int rb = rowb + i * 16;
#pragma unroll
    for (int j = 0; j < 4; ++j) {
      int cc = colb + j * 16;
#pragma unroll
      for (int r = 0; r < 4; ++r) {
        int rr = rb + r;
        if (rr < V_) proj[(size_t)rr * NCOL + cc] = acc[i][j][r];
      }
    }
  }
}

// ---------------------------------------------------------------------------
// Recurrence v5: R0's proven 4-barrier dataflow, re-tiled to 512 threads per
// chain (16-way k-split, kg = tid>>5 over k slices of 8). Per-thread FMA
// halves (gate 64, cand 32) -> per-SIMD issue ~480 cyc/step at the same
// 2 waves/SIMD (1 WG/CU via waves_per_eu(2,2), 8-wave WG). Latency part of
// the step (LDS round-trips + barrier skew) is unchanged; only issue shrinks.
// Partial-reduce is a 4-level tree over 16 independent LDS loads.
// ---------------------------------------------------------------------------
__global__ __attribute__((amdgpu_flat_work_group_size(512, 512),
                          amdgpu_waves_per_eu(2, 2)))
void recur_kernel(
    const int* __restrict__ ctx, const int* __restrict__ endseq,
    const int* __restrict__ ctx_len, const int* __restrict__ end_len,
    const float* __restrict__ proj, const float* __restrict__ Uall,
    const float* __restrict__ bias, float* __restrict__ states) {
  __shared__ __align__(16) float h_s[128];
  __shared__ __align__(16) float rh_s[128];
  __shared__ __align__(16) float u_s[128];
  __shared__ __align__(16) float pg[16][260];
  __shared__ __align__(16) float pc[16][132];

  int bid = blockIdx.x;
  int tid = threadIdx.x;
  const int* seq; int S, L, b, dir; float* stbase;
  if (bid < 256) {
    b = bid >> 1; dir = bid & 1;
    seq = ctx + b * SC_; S = SC_; L = ctx_len[b];
    stbase = states + (dir ? SZ_ST_CTX : 0) + (size_t)b * SC_ * C_;
  } else {
    int q = bid - 256; b = q >> 1; dir = q & 1;
    seq = endseq + b * SE_; S = SE_; L = end_len[b];
    stbase = states + 2*SZ_ST_CTX + (dir ? SZ_ST_END : 0) + (size_t)b * SE_ * C_;
  }
  int dirOff = dir ? 384 : 0;
  int kg = tid >> 5, jg = tid & 31;   // kg: k-slice [kg*8, kg*8+8)

  // weights: gate 8k x 8cols, cand 8k x 4cols (96 floats/thread)
  float wg[8][8];
  float wc[8][4];
#pragma unroll
  for (int kk = 0; kk < 8; ++kk) {
    const float* up = Uall + (size_t)(kg*8 + kk) * NCOL + dirOff;
    float4 w0 = *(const float4*)(up + jg*8);
    float4 w1 = *(const float4*)(up + jg*8 + 4);
    wg[kk][0]=w0.x; wg[kk][1]=w0.y; wg[kk][2]=w0.z; wg[kk][3]=w0.w;
    wg[kk][4]=w1.x; wg[kk][5]=w1.y; wg[kk][6]=w1.z; wg[kk][7]=w1.w;
    float4 wv = *(const float4*)(up + 256 + jg*4);
    wc[kk][0]=wv.x; wc[kk][1]=wv.y; wc[kk][2]=wv.z; wc[kk][3]=wv.w;
  }
  float bias_g = (tid < 256) ? bias[dirOff + tid] : 0.f;
  float bias_c = (tid < 128) ? bias[dirOff + 256 + tid] : 0.f;

  if (tid < 128) h_s[tid] = 0.f;
  __syncthreads();

  // t=0 x row (tid<256 holds xg for col tid; tid<128 also xc)
  int pos0 = dir ? (L - 1) : 0;
  int tok0 = seq[pos0];
  const float* xr0 = proj + (size_t)tok0 * NCOL + dirOff;
  float xg = (tid < 256) ? xr0[tid] : 0.f;
  float xc = (tid < 128) ? xr0[256 + tid] : 0.f;

  for (int t = 0; t < L; ++t) {
    float xg_n = 0.f, xc_n = 0.f;
    if (t + 1 < L) {
      int pos_n = dir ? (L - 2 - t) : (t + 1);
      int tok_n = seq[pos_n];
      const float* xr = proj + (size_t)tok_n * NCOL + dirOff;
      if (tid < 256) xg_n = xr[tid];
      if (tid < 128) xc_n = xr[256 + tid];
    }

    // gate partials: 8 cols x 8 k
    float a[8] = {0.f,0.f,0.f,0.f,0.f,0.f,0.f,0.f};
    const float4* h4 = (const float4*)h_s;
#pragma unroll
    for (int q = 0; q < 2; ++q) {
      float4 hv = h4[kg*2 + q];
      float he[4] = {hv.x, hv.y, hv.z, hv.w};
#pragma unroll
      for (int e = 0; e < 4; ++e)
#pragma unroll
        for (int jj = 0; jj < 8; ++jj)
          a[jj] += he[e] * wg[q*4 + e][jj];
    }
    *(float4*)(&pg[kg][jg*8])     = make_float4(a[0], a[1], a[2], a[3]);
    *(float4*)(&pg[kg][jg*8 + 4]) = make_float4(a[4], a[5], a[6], a[7]);
    __syncthreads();   // B1

    float h_old = 0.f;
    if (tid < 256) {
      float s[16];
#pragma unroll
      for (int k2 = 0; k2 < 16; ++k2) s[k2] = pg[k2][tid];
#pragma unroll
      for (int st = 1; st < 16; st <<= 1)
#pragma unroll
        for (int k2 = 0; k2 < 16; k2 += 2*st) s[k2] += s[k2 + st];
      float g = fast_sigmoid(s[0] + xg + bias_g);
      if (tid < 128) { h_old = h_s[tid]; rh_s[tid] = g * h_old; }
      else           { u_s[tid - 128] = g; }
    }
    __syncthreads();   // B2

    // cand partials: 4 cols x 8 k
    float ac[4] = {0.f, 0.f, 0.f, 0.f};
    const float4* rh4 = (const float4*)rh_s;
#pragma unroll
    for (int q = 0; q < 2; ++q) {
      float4 rv = rh4[kg*2 + q];
      float re[4] = {rv.x, rv.y, rv.z, rv.w};
#pragma unroll
      for (int e = 0; e < 4; ++e)
#pragma unroll
        for (int jj = 0; jj < 4; ++jj)
          ac[jj] += re[e] * wc[q*4 + e][jj];
    }
    *(float4*)(&pc[kg][jg*4]) = make_float4(ac[0], ac[1], ac[2], ac[3]);
    __syncthreads();   // B3

    if (tid < 128) {
      float s[16];
#pragma unroll
      for (int k2 = 0; k2 < 16; ++k2) s[k2] = pc[k2][tid];
#pragma unroll
      for (int st = 1; st < 16; st <<= 1)
#pragma unroll
        for (int k2 = 0; k2 < 16; k2 += 2*st) s[k2] += s[k2 + st];
      float c = fast_tanh(s[0] + xc + bias_c);
      float u = u_s[tid];
      float hn = u * h_old + (1.f - u) * c;
      h_s[tid] = hn;
      int pos = dir ? (L - 1 - t) : t;
      stbase[(size_t)pos * C_ + tid] = hn;
    }
    __syncthreads();   // B4
    xg = xg_n; xc = xc_n;
  }

  for (int i = L * C_ + tid; i < S * C_; i += 512) stbase[i] = 0.f;
}

// ---------------------------------------------------------------------------
// Attention v2 (standalone, proven 67us): MFMA bf16x3 score projection,
// online softmax. Per WG one (b, dir, arr) chain.
// ---------------------------------------------------------------------------
__global__ __launch_bounds__(256, 2) void attn_kernel(
    const float* __restrict__ states, const short* __restrict__ awt_hi,
    const short* __restrict__ awt_lo, const float* __restrict__ att_v,
    const float* __restrict__ att_b, float* __restrict__ feats) {
  __shared__ __align__(16) float st_s[16][132];
  __shared__ __align__(16) short ah_s[16][132];
  __shared__ __align__(16) short al_s[16][132];
  __shared__ float spart[4][16];
  __shared__ float score_s[16];
  __shared__ float cm[128], cl[128], ca[128];

  int bid = blockIdx.x, tid = threadIdx.x;
  int b, dir, S, featOff; const float* stb;
  if (bid < 256) {
    b = bid >> 1; dir = bid & 1; S = SC_;
    stb = states + (dir ? SZ_ST_CTX : 0) + (size_t)b * SC_ * C_;
    featOff = dir * 128;
  } else {
    int q = bid - 256; b = q >> 1; dir = q & 1; S = SE_;
    stb = states + 2*SZ_ST_CTX + (dir ? SZ_ST_END : 0) + (size_t)b * SE_ * C_;
    featOff = 256 + dir * 128;
  }

  int w = tid >> 6, lane = tid & 63;
  int quad = lane >> 4, l15 = lane & 15;

  int d0 = 32 * w + l15, d1 = d0 + 16;
  bf16x8 bh0[4], bh1[4], bl0[4], bl1[4];
#pragma unroll
  for (int kt = 0; kt < 4; ++kt) {
    bh0[kt] = *(const bf16x8*)&awt_hi[d0*128 + kt*32 + quad*8];
    bh1[kt] = *(const bf16x8*)&awt_hi[d1*128 + kt*32 + quad*8];
    bl0[kt] = *(const bf16x8*)&awt_lo[d0*128 + kt*32 + quad*8];
    bl1[kt] = *(const bf16x8*)&awt_lo[d1*128 + kt*32 + quad*8];
  }
  float vv0 = att_v[d0], vv1 = att_v[d1];
  float bb0 = att_b[d0], bb1 = att_b[d1];

  int c = tid & 127, half = tid >> 7;
  float m = -1e30f, lsum = 0.f, acc = 0.f;

  int lrow = tid >> 4, lcol = (tid & 15) * 8;
  float4 p0, p1;
  {
    const float* src = stb + (size_t)lrow * C_ + lcol;
    p0 = *(const float4*)(src);
    p1 = *(const float4*)(src + 4);
  }

  int nchunks = S >> 4;
  for (int ch = 0; ch < nchunks; ++ch) {
    __syncthreads();   // B0
    float f[8] = {p0.x, p0.y, p0.z, p0.w, p1.x, p1.y, p1.z, p1.w};
    short hi8[8], lo8[8];
#pragma unroll
    for (int j = 0; j < 8; ++j) {
      unsigned short h = f2bf_rne(f[j]);
      float hf = __uint_as_float((unsigned)h << 16);
      hi8[j] = (short)h;
      lo8[j] = (short)f2bf_rne(f[j] - hf);
    }
    *(float4*)(&st_s[lrow][lcol])     = p0;
    *(float4*)(&st_s[lrow][lcol + 4]) = p1;
    *(bf16x8*)(&ah_s[lrow][lcol]) = *(bf16x8*)hi8;
    *(bf16x8*)(&al_s[lrow][lcol]) = *(bf16x8*)lo8;
    if (ch + 1 < nchunks) {
      const float* src = stb + (size_t)((ch + 1) * 16 + lrow) * C_ + lcol;
      p0 = *(const float4*)(src);
      p1 = *(const float4*)(src + 4);
    }
    __syncthreads();   // B1

    f32x4 ac0 = {0.f, 0.f, 0.f, 0.f}, ac1 = {0.f, 0.f, 0.f, 0.f};
#pragma unroll
    for (int kt = 0; kt < 4; ++kt) {
      bf16x8 a_hi = *(bf16x8*)&ah_s[l15][kt*32 + quad*8];
      bf16x8 a_lo = *(bf16x8*)&al_s[l15][kt*32 + quad*8];
      ac0 = __builtin_amdgcn_mfma_f32_16x16x32_bf16(a_hi, bh0[kt], ac0, 0, 0, 0);
      ac0 = __builtin_amdgcn_mfma_f32_16x16x32_bf16(a_hi, bl0[kt], ac0, 0, 0, 0);
      ac0 = __builtin_amdgcn_mfma_f32_16x16x32_bf16(a_lo, bh0[kt], ac0, 0, 0, 0);
      ac1 = __builtin_amdgcn_mfma_f32_16x16x32_bf16(a_hi, bh1[kt], ac1, 0, 0, 0);
      ac1 = __builtin_amdgcn_mfma_f32_16x16x32_bf16(a_hi, bl1[kt], ac1, 0, 0, 0);
      ac1 = __builtin_amdgcn_mfma_f32_16x16x32_bf16(a_lo, bh1[kt], ac1, 0, 0, 0);
    }

    float part[4];
#pragma unroll
    for (int r = 0; r < 4; ++r)
      part[r] = fast_tanh(ac0[r] + bb0) * vv0 + fast_tanh(ac1[r] + bb1) * vv1;
#pragma unroll
    for (int mask = 1; mask <= 8; mask <<= 1)
#pragma unroll
      for (int r = 0; r < 4; ++r)
        part[r] += __shfl_xor(part[r], mask, 64);
    if (l15 == 0) {
#pragma unroll
      for (int r = 0; r < 4; ++r) spart[w][quad*4 + r] = part[r];
    }
    __syncthreads();   // B2
    if (tid < 16)
      score_s[tid] = spart[0][tid] + spart[1][tid] + spart[2][tid] + spart[3][tid];
    __syncthreads();   // B3

    float srow[8]; float smax = m;
#pragma unroll
    for (int r = 0; r < 8; ++r) { srow[r] = score_s[half*8 + r]; smax = fmaxf(smax, srow[r]); }
    float scale = __expf(m - smax);
    acc *= scale; lsum *= scale; m = smax;
#pragma unroll
    for (int r = 0; r < 8; ++r) {
      float wgt = __expf(srow[r] - m);
      lsum += wgt;
      acc += wgt * st_s[half*8 + r][c];
    }
  }

  __syncthreads();
  if (half == 1) { cm[c] = m; cl[c] = lsum; ca[c] = acc; }
  __syncthreads();
  if (half == 0) {
    float m1 = cm[c], l1 = cl[c], a1 = ca[c];
    float M = fmaxf(m, m1);
    float w0 = __expf(m - M), w1 = __expf(m1 - M);
    feats[b * 512 + featOff + c] = (acc * w0 + a1 * w1) / (lsum * w0 + l1 * w1);
  }
}

// ---------------------------------------------------------------------------
// Head
// ---------------------------------------------------------------------------
__global__ __launch_bounds__(128) void head_kernel(
    const float* __restrict__ feats, const float* __restrict__ hid_w,
    const float* __restrict__ hid_b, const float* __restrict__ out_w,
    const float* __restrict__ out_b, float* __restrict__ out) {
  __shared__ __align__(16) float f_s[512];
  __shared__ float part[2];
  int b = blockIdx.x, tid = threadIdx.x;
  for (int i = tid; i < 512; i += 128) f_s[i] = feats[b * 512 + i];
  __syncthreads();
  float h = hid_b[tid];
  for (int k = 0; k < 512; ++k) h += f_s[k] * hid_w[k * 128 + tid];
  h = fmaxf(h, 0.f);
  float p = h * out_w[tid];
#pragma unroll
  for (int off = 32; off > 0; off >>= 1) p += __shfl_xor(p, off, 64);
  if ((tid & 63) == 0) part[tid >> 6] = p;
  __syncthreads();
  if (tid == 0) out[b] = part[0] + part[1] + out_b[0];
}

// ---------------------------------------------------------------------------
extern "C" void kernel_launch(void* const* d_in, const int* in_sizes, int n_in,
                              void* d_out, int out_size, void* d_ws, size_t ws_size,
                              hipStream_t stream) {
  const int*   ctx     = (const int*)d_in[0];
  const int*   endseq  = (const int*)d_in[1];
  const int*   ctx_len = (const int*)d_in[2];
  const int*   end_len = (const int*)d_in[3];
  const float* emb     = (const float*)d_in[4];
  const float* fw_gw   = (const float*)d_in[5];
  const float* fw_gb   = (const float*)d_in[6];
  const float* fw_cw   = (const float*)d_in[7];
  const float* fw_cb   = (const float*)d_in[8];
  const float* bw_gw   = (const float*)d_in[9];
  const float* bw_gb   = (const float*)d_in[10];
  const float* bw_cw   = (const float*)d_in[11];
  const float* bw_cb   = (const float*)d_in[12];
  const float* att_v   = (const float*)d_in[13];
  const float* att_w   = (const float*)d_in[14];
  const float* att_b   = (const float*)d_in[15];
  const float* hid_w   = (const float*)d_in[16];
  const float* hid_b   = (const float*)d_in[17];
  const float* out_w   = (const float*)d_in[18];
  const float* out_b   = (const float*)d_in[19];
  float* ws  = (float*)d_ws;
  float* out = (float*)d_out;

  short* Ahi    = (short*)(ws + OFF_ST);
  short* Alo    = Ahi + (size_t)V_ * KP;
  short* Bthi   = (short*)(ws + OFF_BT);
  short* Btlo   = Bthi + (size_t)NCOL * KP;
  short* awt_hi = (short*)(ws + OFF_AWT);
  short* awt_lo = awt_hi + 128 * 128;

  pack_kernel<<<1299, 256, 0, stream>>>(fw_gw, fw_gb, fw_cw, fw_cb,
                                        bw_gw, bw_gb, bw_cw, bw_cb, ws);
  pack_bt<<<(NCOL * KP + 128 * 128 + 255) / 256, 256, 0, stream>>>(
      ws + OFF_WXP, Bthi, Btlo, att_w, awt_hi, awt_lo);
  pack_emb<<<(int)(((size_t)V_ * KP + 255) / 256), 256, 0, stream>>>(emb, Ahi, Alo);

  gemm_mfma<<<2346, 256, 0, stream>>>(Ahi, Alo, Bthi, Btlo, ws + OFF_PROJ);

  recur_kernel<<<512, 512, 0, stream>>>(ctx, endseq, ctx_len, end_len,
                                        ws + OFF_PROJ, ws + OFF_UALL,
                                        ws + OFF_BIAS, ws + OFF_ST);

  attn_kernel<<<512, 256, 0, stream>>>(ws + OFF_ST, awt_hi, awt_lo,
                                       att_v, att_b, ws + OFF_FEATS);

  head_kernel<<<128, 128, 0, stream>>>(ws + OFF_FEATS, hid_w, hid_b,
                                       out_w, out_b, out);
}

// Round 8
// 739.871 us; speedup vs baseline: 2.8139x; 1.0412x over previous
//
#include <hip/hip_runtime.h>
#include <cstdint>
#include <cmath>

// Problem constants
static constexpr int V_  = 50000;
static constexpr int E_  = 300;
static constexpr int C_  = 128;
static constexpr int B_  = 128;
static constexpr int SC_ = 512;
static constexpr int SE_ = 64;
static constexpr int NCOL = 768;   // [fw_gate 256 | fw_cand 128 | bw_gate 256 | bw_cand 128]
static constexpr int KP  = 320;    // K padded to 10 x 32 for MFMA

// ws layout (float offsets)
static constexpr size_t OFF_PROJ  = 0;
static constexpr size_t SZ_PROJ   = (size_t)V_ * NCOL;
static constexpr size_t OFF_WXP   = OFF_PROJ + SZ_PROJ;
static constexpr size_t SZ_WXP    = (size_t)304 * NCOL;
static constexpr size_t OFF_UALL  = OFF_WXP + SZ_WXP;
static constexpr size_t SZ_UALL   = (size_t)C_ * NCOL;
static constexpr size_t OFF_BIAS  = OFF_UALL + SZ_UALL;
static constexpr size_t SZ_BIAS   = NCOL;
static constexpr size_t OFF_ST    = OFF_BIAS + SZ_BIAS;
static constexpr size_t SZ_ST_CTX = (size_t)B_ * SC_ * C_;
static constexpr size_t SZ_ST_END = (size_t)B_ * SE_ * C_;
static constexpr size_t SZ_ST     = 2*SZ_ST_CTX + 2*SZ_ST_END;    // 75.5 MB
static constexpr size_t OFF_FEATS = OFF_ST + SZ_ST;
static constexpr size_t SZ_FEATS  = (size_t)B_ * 512;
static constexpr size_t OFF_BT    = OFF_FEATS + SZ_FEATS;
static constexpr size_t SZ_BT     = (size_t)NCOL * KP / 2 * 2;    // 2 short arrays (245760 floats)
static constexpr size_t OFF_AWT   = OFF_BT + SZ_BT;               // att_w^T hi/lo shorts
// Partials buffer for split attention REUSES the Bt region (dead after gemm):
// 512 chains x 2 halves x (m, l, acc[128]) = 133120 floats < 245760.
// A_hi/A_lo (bf16) OVERLAP the states region (dead once gemm ends; recur
// zeroes its own tail rows so no global memset is needed).

typedef __attribute__((ext_vector_type(8))) short bf16x8;
typedef __attribute__((ext_vector_type(4))) float f32x4;

static __device__ __forceinline__ unsigned short f2bf_rne(float f) {
  unsigned u = __float_as_uint(f);
  unsigned r = u + 0x7fffu + ((u >> 16) & 1u);
  return (unsigned short)(r >> 16);
}

static __device__ __forceinline__ void gload_lds16(const short* g, short* l) {
  __builtin_amdgcn_global_load_lds(
      (const __attribute__((address_space(1))) void*)g,
      (__attribute__((address_space(3))) void*)l, 16, 0, 0);
}

// fast activations: __expf + v_rcp_f32 (~1e-6 rel err; logit threshold 7.4e-5)
static __device__ __forceinline__ float fast_sigmoid(float x) {
  return __builtin_amdgcn_rcpf(1.f + __expf(-x));
}
static __device__ __forceinline__ float fast_tanh(float x) {
  return fmaf(-2.f, __builtin_amdgcn_rcpf(__expf(2.f * x) + 1.f), 1.f);
}

// ---------------------------------------------------------------------------
// Pack: Wxp[304][768] fp32, Uall[128][768], bias[768]
// ---------------------------------------------------------------------------
__global__ void pack_kernel(const float* __restrict__ fw_gw, const float* __restrict__ fw_gb,
                            const float* __restrict__ fw_cw, const float* __restrict__ fw_cb,
                            const float* __restrict__ bw_gw, const float* __restrict__ bw_gb,
                            const float* __restrict__ bw_cw, const float* __restrict__ bw_cb,
                            float* __restrict__ ws) {
  int i = blockIdx.x * 256 + threadIdx.x;
  float* Wxp  = ws + OFF_WXP;
  float* Uall = ws + OFF_UALL;
  float* bias = ws + OFF_BIAS;
  if (i < 304 * NCOL) {
    int k = i / NCOL, c = i % NCOL;
    float v = 0.f;
    if (k < 300) {
      if (c < 256)      v = fw_gw[k*256 + c];
      else if (c < 384) v = fw_cw[k*128 + (c-256)];
      else if (c < 640) v = bw_gw[k*256 + (c-384)];
      else              v = bw_cw[k*128 + (c-640)];
    }
    Wxp[i] = v;
    return;
  }
  int j = i - 304 * NCOL;
  if (j >= 0 && j < 128 * NCOL) {
    int k = j / NCOL, c = j % NCOL;
    int kk = 300 + k;
    float v;
    if (c < 256)      v = fw_gw[kk*256 + c];
    else if (c < 384) v = fw_cw[kk*128 + (c-256)];
    else if (c < 640) v = bw_gw[kk*256 + (c-384)];
    else              v = bw_cw[kk*128 + (c-640)];
    Uall[j] = v;
    return;
  }
  int m = j - 128 * NCOL;
  if (m >= 0 && m < NCOL) {
    float v;
    if (m < 256)      v = fw_gb[m];
    else if (m < 384) v = fw_cb[m-256];
    else if (m < 640) v = bw_gb[m-384];
    else              v = bw_cb[m-640];
    bias[m] = v;
  }
}

// Bt hi/lo for the proj GEMM + att_w^T hi/lo for the MFMA attention
__global__ void pack_bt(const float* __restrict__ Wxp, short* __restrict__ Bthi,
                        short* __restrict__ Btlo, const float* __restrict__ att_w,
                        short* __restrict__ awt_hi, short* __restrict__ awt_lo) {
  int i = blockIdx.x * 256 + threadIdx.x;
  if (i < NCOL * KP) {
    int k = i % KP, n = i / KP;
    float v = (k < 304) ? Wxp[(size_t)k * NCOL + n] : 0.f;
    unsigned short h = f2bf_rne(v);
    float hf = __uint_as_float((unsigned)h << 16);
    unsigned short lo = f2bf_rne(v - hf);
    Bthi[i] = (short)h;
    Btlo[i] = (short)lo;
    return;
  }
  int j = i - NCOL * KP;
  if (j < 128 * 128) {
    int d = j >> 7, c = j & 127;
    float v = att_w[(size_t)c * 128 + d];   // transpose: awt[d][k=c]
    unsigned short h = f2bf_rne(v);
    float hf = __uint_as_float((unsigned)h << 16);
    unsigned short lo = f2bf_rne(v - hf);
    awt_hi[j] = (short)h;
    awt_lo[j] = (short)lo;
  }
}

__global__ void pack_emb(const float* __restrict__ emb, short* __restrict__ Ahi,
                         short* __restrict__ Alo) {
  size_t i = (size_t)blockIdx.x * 256 + threadIdx.x;
  if (i >= (size_t)V_ * KP) return;
  int k = (int)(i % KP);
  size_t row = i / KP;
  float v = (k < E_) ? emb[row * E_ + k] : 0.f;
  unsigned short h = f2bf_rne(v);
  float hf = __uint_as_float((unsigned)h << 16);
  unsigned short lo = f2bf_rne(v - hf);
  Ahi[i] = (short)h;
  Alo[i] = (short)lo;
}

// ---------------------------------------------------------------------------
// proj = emb @ Wxp via bf16x3 split MFMA (m97 structure). Linear grid +
// bijective XCD swizzle (m204): all 6 n-blocks of one m-tile on one XCD.
// ---------------------------------------------------------------------------
__global__ __launch_bounds__(256) void gemm_mfma(
    const short* __restrict__ Ahi, const short* __restrict__ Alo,
    const short* __restrict__ Bthi, const short* __restrict__ Btlo,
    float* __restrict__ proj) {
  __shared__ short lds[16384];
  int tid = threadIdx.x, wid = tid >> 6, lane = tid & 63;

  // bijective XCD swizzle: nwg=2346, q=293, r=2
  int bid = blockIdx.x;
  int xcd = bid & 7, idx = bid >> 3;
  int wgid = (xcd < 2 ? xcd * 294 : 588 + (xcd - 2) * 293) + idx;
  int m0 = (wgid / 6) * 128;
  int n0 = (wgid % 6) * 128;

  f32x4 acc[4][4] = {};

  int lr = lane >> 2, lc = lane & 3;
  int q0 = wid * 2, q1 = q0 + 1;
  int r0 = q0 * 16 + lr, r1 = q1 * 16 + lr;
  int am0 = m0 + r0; if (am0 > V_ - 1) am0 = V_ - 1;
  int am1 = m0 + r1; if (am1 > V_ - 1) am1 = V_ - 1;
  size_t gaOff0 = (size_t)am0 * KP + lc * 8;
  size_t gaOff1 = (size_t)am1 * KP + lc * 8;
  size_t gbOff0 = (size_t)(n0 + r0) * KP + lc * 8;
  size_t gbOff1 = (size_t)(n0 + r1) * KP + lc * 8;

  int quad = lane >> 4;
  int arow = (wid >> 1) * 64 + (lane & 15);
  int brow = (wid & 1) * 64 + (lane & 15);

  for (int k0 = 0; k0 < KP; k0 += 32) {
    gload_lds16(Ahi  + gaOff0 + k0, lds +         q0 * 512);
    gload_lds16(Ahi  + gaOff1 + k0, lds +         q1 * 512);
    gload_lds16(Alo  + gaOff0 + k0, lds +  4096 + q0 * 512);
    gload_lds16(Alo  + gaOff1 + k0, lds +  4096 + q1 * 512);
    gload_lds16(Bthi + gbOff0 + k0, lds +  8192 + q0 * 512);
    gload_lds16(Bthi + gbOff1 + k0, lds +  8192 + q1 * 512);
    gload_lds16(Btlo + gbOff0 + k0, lds + 12288 + q0 * 512);
    gload_lds16(Btlo + gbOff1 + k0, lds + 12288 + q1 * 512);
    __syncthreads();

    bf16x8 ah[4], al[4], bh[4], bl[4];
#pragma unroll
    for (int i = 0; i < 4; ++i) {
      ah[i] = *(bf16x8*)&lds[        (arow + i*16) * 32 + quad * 8];
      al[i] = *(bf16x8*)&lds[ 4096 + (arow + i*16) * 32 + quad * 8];
      bh[i] = *(bf16x8*)&lds[ 8192 + (brow + i*16) * 32 + quad * 8];
      bl[i] = *(bf16x8*)&lds[12288 + (brow + i*16) * 32 + quad * 8];
    }
#pragma unroll
    for (int i = 0; i < 4; ++i)
#pragma unroll
      for (int j = 0; j < 4; ++j) {
        acc[i][j] = __builtin_amdgcn_mfma_f32_16x16x32_bf16(ah[i], bh[j], acc[i][j], 0, 0, 0);
        acc[i][j] = __builtin_amdgcn_mfma_f32_16x16x32_bf16(ah[i], bl[j], acc[i][j], 0, 0, 0);
        acc[i][j] = __builtin_amdgcn_mfma_f32_16x16x32_bf16(al[i], bh[j], acc[i][j], 0, 0, 0);
      }
    __syncthreads();
  }

  int colb = n0 + (wid & 1) * 64 + (lane & 15);
  int rowb = m0 + (wid >> 1) * 64 + quad * 4;
#pragma unroll
  for (int i = 0; i < 4; ++i) {
    int rb = rowb + i * 16;
#pragma unroll
    for (int j = 0; j < 4; ++j) {
      int cc = colb + j * 16;
#pragma unroll
      for (int r = 0; r < 4; ++r) {
        int rr = rb + r;
        if (rr < V_) proj[(size_t)rr * NCOL + cc] = acc[i][j][r];
      }
    }
  }
}

// ---------------------------------------------------------------------------
// Recurrence: round-0 best-measured body VERBATIM (466 us). Six structural
// variants (R1-R6: pair-fuse, shuffle-reduce, attn-fuse, MFMA-batch, LDS-only
// barriers, 512-thread) all landed 501-1835 us — the 4-barrier chain-per-WG
// step (~910 ns) is latency-structural, not issue- or barrier-count-bound.
// ---------------------------------------------------------------------------
__global__ __attribute__((amdgpu_flat_work_group_size(256, 256),
                          amdgpu_waves_per_eu(2, 2)))
void recur_kernel(
    const int* __restrict__ ctx, const int* __restrict__ endseq,
    const int* __restrict__ ctx_len, const int* __restrict__ end_len,
    const float* __restrict__ proj, const float* __restrict__ Uall,
    const float* __restrict__ bias, float* __restrict__ states) {
  __shared__ __align__(16) float h_s[128];
  __shared__ __align__(16) float rh_s[128];
  __shared__ __align__(16) float u_s[128];
  __shared__ __align__(16) float pg[8][260];
  __shared__ __align__(16) float pc[8][132];

  int bid = blockIdx.x;
  int tid = threadIdx.x;
  const int* seq; int S, L, b, dir; float* stbase;
  if (bid < 256) {
    b = bid >> 1; dir = bid & 1;
    seq = ctx + b * SC_; S = SC_; L = ctx_len[b];
    stbase = states + (dir ? SZ_ST_CTX : 0) + (size_t)b * SC_ * C_;
  } else {
    int q = bid - 256; b = q >> 1; dir = q & 1;
    seq = endseq + b * SE_; S = SE_; L = end_len[b];
    stbase = states + 2*SZ_ST_CTX + (dir ? SZ_ST_END : 0) + (size_t)b * SE_ * C_;
  }
  int dirOff = dir ? 384 : 0;
  int kg = tid >> 5, jg = tid & 31;

  float wg[16][8];
  float wc[16][4];
#pragma unroll
  for (int kk = 0; kk < 16; ++kk) {
    const float* up = Uall + (size_t)(kg*16 + kk) * NCOL + dirOff;
    float4 w0 = *(const float4*)(up + jg*8);
    float4 w1 = *(const float4*)(up + jg*8 + 4);
    wg[kk][0]=w0.x; wg[kk][1]=w0.y; wg[kk][2]=w0.z; wg[kk][3]=w0.w;
    wg[kk][4]=w1.x; wg[kk][5]=w1.y; wg[kk][6]=w1.z; wg[kk][7]=w1.w;
    float4 wv = *(const float4*)(up + 256 + jg*4);
    wc[kk][0]=wv.x; wc[kk][1]=wv.y; wc[kk][2]=wv.z; wc[kk][3]=wv.w;
  }
  float bias_g = bias[dirOff + tid];
  float bias_c = (tid < 128) ? bias[dirOff + 256 + tid] : 0.f;

  if (tid < 128) h_s[tid] = 0.f;
  __syncthreads();

  int pos0 = dir ? (L - 1) : 0;
  int tok0 = seq[pos0];
  const float* xr0 = proj + (size_t)tok0 * NCOL + dirOff;
  float xg = xr0[tid];
  float xc = (tid < 128) ? xr0[256 + tid] : 0.f;

  for (int t = 0; t < L; ++t) {
    float xg_n = 0.f, xc_n = 0.f;
    if (t + 1 < L) {
      int pos_n = dir ? (L - 2 - t) : (t + 1);
      int tok_n = seq[pos_n];
      const float* xr = proj + (size_t)tok_n * NCOL + dirOff;
      xg_n = xr[tid];
      xc_n = (tid < 128) ? xr[256 + tid] : 0.f;
    }

    float a[8] = {0.f,0.f,0.f,0.f,0.f,0.f,0.f,0.f};
    const float4* h4 = (const float4*)h_s;
#pragma unroll
    for (int q = 0; q < 4; ++q) {
      float4 hv = h4[kg*4 + q];
      float he[4] = {hv.x, hv.y, hv.z, hv.w};
#pragma unroll
      for (int e = 0; e < 4; ++e)
#pragma unroll
        for (int jj = 0; jj < 8; ++jj)
          a[jj] += he[e] * wg[q*4 + e][jj];
    }
    *(float4*)(&pg[kg][jg*8])     = make_float4(a[0], a[1], a[2], a[3]);
    *(float4*)(&pg[kg][jg*8 + 4]) = make_float4(a[4], a[5], a[6], a[7]);
    __syncthreads();   // B1

    float g = xg + bias_g;
#pragma unroll
    for (int k2 = 0; k2 < 8; ++k2) g += pg[k2][tid];
    g = fast_sigmoid(g);

    float h_old = 0.f;
    if (tid < 128) { h_old = h_s[tid]; rh_s[tid] = g * h_old; }
    else           { u_s[tid - 128] = g; }
    __syncthreads();   // B2

    float ac[4] = {0.f, 0.f, 0.f, 0.f};
    const float4* rh4 = (const float4*)rh_s;
#pragma unroll
    for (int q = 0; q < 4; ++q) {
      float4 rv = rh4[kg*4 + q];
      float re[4] = {rv.x, rv.y, rv.z, rv.w};
#pragma unroll
      for (int e = 0; e < 4; ++e)
#pragma unroll
        for (int jj = 0; jj < 4; ++jj)
          ac[jj] += re[e] * wc[q*4 + e][jj];
    }
    *(float4*)(&pc[kg][jg*4]) = make_float4(ac[0], ac[1], ac[2], ac[3]);
    __syncthreads();   // B3

    if (tid < 128) {
      float cs = xc + bias_c;
#pragma unroll
      for (int k2 = 0; k2 < 8; ++k2) cs += pc[k2][tid];
      float c = fast_tanh(cs);
      float u = u_s[tid];
      float hn = u * h_old + (1.f - u) * c;
      h_s[tid] = hn;
      int pos = dir ? (L - 1 - t) : t;
      stbase[(size_t)pos * C_ + tid] = hn;
    }
    __syncthreads();   // B4
    xg = xg_n; xc = xc_n;
  }

  for (int i = L * C_ + tid; i < S * C_; i += 256) stbase[i] = 0.f;
}

// ---------------------------------------------------------------------------
// Attention v3: SPLIT across chunk halves. ctx chains get 2 WGs (16 chunks
// each); end chains 1 WG (4 chunks). Grid 768, launch_bounds(256,3) -> 3
// WGs/CU (vs 2 before) for better latency hiding of the per-chunk barrier
// chain. Each WG emits an online-softmax partial triple (m, l, acc[128]) to
// the partials buffer (reused Bt region); attn_merge combines per chain.
// ---------------------------------------------------------------------------
__global__ __launch_bounds__(256, 3) void attn_kernel(
    const float* __restrict__ states, const short* __restrict__ awt_hi,
    const short* __restrict__ awt_lo, const float* __restrict__ att_v,
    const float* __restrict__ att_b, float* __restrict__ partials) {
  __shared__ __align__(16) float st_s[16][132];
  __shared__ __align__(16) short ah_s[16][132];
  __shared__ __align__(16) short al_s[16][132];
  __shared__ float spart[4][16];
  __shared__ float score_s[16];
  __shared__ float cm[128], cl[128], ca[128];

  int bid = blockIdx.x, tid = threadIdx.x;
  int b, dir, S, pchain, ph, ch0, ch1, isEndWG; const float* stb;
  if (bid < 512) {            // ctx: 256 chains x 2 halves
    int chain = bid >> 1;  ph = bid & 1;
    b = chain >> 1; dir = chain & 1; S = SC_;
    stb = states + (dir ? SZ_ST_CTX : 0) + (size_t)b * SC_ * C_;
    pchain = chain; ch0 = ph * 16; ch1 = ch0 + 16; isEndWG = 0;
  } else {                    // end: 256 chains x 1 WG
    int e = bid - 512;
    b = e >> 1; dir = e & 1; S = SE_;
    stb = states + 2*SZ_ST_CTX + (dir ? SZ_ST_END : 0) + (size_t)b * SE_ * C_;
    pchain = 256 + e; ph = 0; ch0 = 0; ch1 = SE_ >> 4; isEndWG = 1;
  }
  (void)S;

  int w = tid >> 6, lane = tid & 63;
  int quad = lane >> 4, l15 = lane & 15;

  int d0 = 32 * w + l15, d1 = d0 + 16;
  bf16x8 bh0[4], bh1[4], bl0[4], bl1[4];
#pragma unroll
  for (int kt = 0; kt < 4; ++kt) {
    bh0[kt] = *(const bf16x8*)&awt_hi[d0*128 + kt*32 + quad*8];
    bh1[kt] = *(const bf16x8*)&awt_hi[d1*128 + kt*32 + quad*8];
    bl0[kt] = *(const bf16x8*)&awt_lo[d0*128 + kt*32 + quad*8];
    bl1[kt] = *(const bf16x8*)&awt_lo[d1*128 + kt*32 + quad*8];
  }
  float vv0 = att_v[d0], vv1 = att_v[d1];
  float bb0 = att_b[d0], bb1 = att_b[d1];

  int c = tid & 127, half = tid >> 7;
  float m = -1e30f, lsum = 0.f, acc = 0.f;

  int lrow = tid >> 4, lcol = (tid & 15) * 8;
  float4 p0, p1;
  {
    const float* src = stb + (size_t)(ch0 * 16 + lrow) * C_ + lcol;
    p0 = *(const float4*)(src);
    p1 = *(const float4*)(src + 4);
  }

  for (int ch = ch0; ch < ch1; ++ch) {
    __syncthreads();   // B0
    float f[8] = {p0.x, p0.y, p0.z, p0.w, p1.x, p1.y, p1.z, p1.w};
    short hi8[8], lo8[8];
#pragma unroll
    for (int j = 0; j < 8; ++j) {
      unsigned short h = f2bf_rne(f[j]);
      float hf = __uint_as_float((unsigned)h << 16);
      hi8[j] = (short)h;
      lo8[j] = (short)f2bf_rne(f[j] - hf);
    }
    *(float4*)(&st_s[lrow][lcol])     = p0;
    *(float4*)(&st_s[lrow][lcol + 4]) = p1;
    *(bf16x8*)(&ah_s[lrow][lcol]) = *(bf16x8*)hi8;
    *(bf16x8*)(&al_s[lrow][lcol]) = *(bf16x8*)lo8;
    if (ch + 1 < ch1) {
      const float* src = stb + (size_t)((ch + 1) * 16 + lrow) * C_ + lcol;
      p0 = *(const float4*)(src);
      p1 = *(const float4*)(src + 4);
    }
    __syncthreads();   // B1

    f32x4 ac0 = {0.f, 0.f, 0.f, 0.f}, ac1 = {0.f, 0.f, 0.f, 0.f};
#pragma unroll
    for (int kt = 0; kt < 4; ++kt) {
      bf16x8 a_hi = *(bf16x8*)&ah_s[l15][kt*32 + quad*8];
      bf16x8 a_lo = *(bf16x8*)&al_s[l15][kt*32 + quad*8];
      ac0 = __builtin_amdgcn_mfma_f32_16x16x32_bf16(a_hi, bh0[kt], ac0, 0, 0, 0);
      ac0 = __builtin_amdgcn_mfma_f32_16x16x32_bf16(a_hi, bl0[kt], ac0, 0, 0, 0);
      ac0 = __builtin_amdgcn_mfma_f32_16x16x32_bf16(a_lo, bh0[kt], ac0, 0, 0, 0);
      ac1 = __builtin_amdgcn_mfma_f32_16x16x32_bf16(a_hi, bh1[kt], ac1, 0, 0, 0);
      ac1 = __builtin_amdgcn_mfma_f32_16x16x32_bf16(a_hi, bl1[kt], ac1, 0, 0, 0);
      ac1 = __builtin_amdgcn_mfma_f32_16x16x32_bf16(a_lo, bh1[kt], ac1, 0, 0, 0);
    }

    float part[4];
#pragma unroll
    for (int r = 0; r < 4; ++r)
      part[r] = fast_tanh(ac0[r] + bb0) * vv0 + fast_tanh(ac1[r] + bb1) * vv1;
#pragma unroll
    for (int mask = 1; mask <= 8; mask <<= 1)
#pragma unroll
      for (int r = 0; r < 4; ++r)
        part[r] += __shfl_xor(part[r], mask, 64);
    if (l15 == 0) {
#pragma unroll
      for (int r = 0; r < 4; ++r) spart[w][quad*4 + r] = part[r];
    }
    __syncthreads();   // B2
    if (tid < 16)
      score_s[tid] = spart[0][tid] + spart[1][tid] + spart[2][tid] + spart[3][tid];
    __syncthreads();   // B3

    float srow[8]; float smax = m;
#pragma unroll
    for (int r = 0; r < 8; ++r) { srow[r] = score_s[half*8 + r]; smax = fmaxf(smax, srow[r]); }
    float scale = __expf(m - smax);
    acc *= scale; lsum *= scale; m = smax;
#pragma unroll
    for (int r = 0; r < 8; ++r) {
      float wgt = __expf(srow[r] - m);
      lsum += wgt;
      acc += wgt * st_s[half*8 + r][c];
    }
  }

  __syncthreads();
  if (half == 1) { cm[c] = m; cl[c] = lsum; ca[c] = acc; }
  __syncthreads();
  if (half == 0) {
    float m1 = cm[c], l1 = cl[c], a1 = ca[c];
    float M = fmaxf(m, m1);
    float w0 = __expf(m - M), w1 = __expf(m1 - M);
    float Lt = lsum * w0 + l1 * w1;
    float At = acc * w0 + a1 * w1;
    float* p = partials + ((size_t)pchain * 2 + ph) * 130;
    if (c == 0) { p[0] = M; p[1] = Lt; }
    p[2 + c] = At;
    if (isEndWG) {   // neutral second half so merge is uniform
      float* pn = partials + ((size_t)pchain * 2 + 1) * 130;
      if (c == 0) { pn[0] = -1e30f; pn[1] = 0.f; }
      pn[2 + c] = 0.f;
    }
  }
}

// Combine the two partial triples of each chain into feats.
__global__ __launch_bounds__(128) void attn_merge_kernel(
    const float* __restrict__ partials, float* __restrict__ feats) {
  int q = blockIdx.x, c = threadIdx.x;
  const float* p0 = partials + (size_t)q * 2 * 130;
  const float* p1 = p0 + 130;
  float m0 = p0[0], l0 = p0[1], a0 = p0[2 + c];
  float m1 = p1[0], l1 = p1[1], a1 = p1[2 + c];
  float M = fmaxf(m0, m1);
  float w0 = __expf(m0 - M), w1 = __expf(m1 - M);
  int b, off;
  if (q < 256) { b = q >> 1; off = (q & 1) * 128; }
  else { int e = q - 256; b = e >> 1; off = 256 + (e & 1) * 128; }
  feats[b * 512 + off + c] = (a0 * w0 + a1 * w1) / (l0 * w0 + l1 * w1);
}

// ---------------------------------------------------------------------------
// Head
// ---------------------------------------------------------------------------
__global__ __launch_bounds__(128) void head_kernel(
    const float* __restrict__ feats, const float* __restrict__ hid_w,
    const float* __restrict__ hid_b, const float* __restrict__ out_w,
    const float* __restrict__ out_b, float* __restrict__ out) {
  __shared__ __align__(16) float f_s[512];
  __shared__ float part[2];
  int b = blockIdx.x, tid = threadIdx.x;
  for (int i = tid; i < 512; i += 128) f_s[i] = feats[b * 512 + i];
  __syncthreads();
  float h = hid_b[tid];
  for (int k = 0; k < 512; ++k) h += f_s[k] * hid_w[k * 128 + tid];
  h = fmaxf(h, 0.f);
  float p = h * out_w[tid];
#pragma unroll
  for (int off = 32; off > 0; off >>= 1) p += __shfl_xor(p, off, 64);
  if ((tid & 63) == 0) part[tid >> 6] = p;
  __syncthreads();
  if (tid == 0) out[b] = part[0] + part[1] + out_b[0];
}

// ---------------------------------------------------------------------------
extern "C" void kernel_launch(void* const* d_in, const int* in_sizes, int n_in,
                              void* d_out, int out_size, void* d_ws, size_t ws_size,
                              hipStream_t stream) {
  const int*   ctx     = (const int*)d_in[0];
  const int*   endseq  = (const int*)d_in[1];
  const int*   ctx_len = (const int*)d_in[2];
  const int*   end_len = (const int*)d_in[3];
  const float* emb     = (const float*)d_in[4];
  const float* fw_gw   = (const float*)d_in[5];
  const float* fw_gb   = (const float*)d_in[6];
  const float* fw_cw   = (const float*)d_in[7];
  const float* fw_cb   = (const float*)d_in[8];
  const float* bw_gw   = (const float*)d_in[9];
  const float* bw_gb   = (const float*)d_in[10];
  const float* bw_cw   = (const float*)d_in[11];
  const float* bw_cb   = (const float*)d_in[12];
  const float* att_v   = (const float*)d_in[13];
  const float* att_w   = (const float*)d_in[14];
  const float* att_b   = (const float*)d_in[15];
  const float* hid_w   = (const float*)d_in[16];
  const float* hid_b   = (const float*)d_in[17];
  const float* out_w   = (const float*)d_in[18];
  const float* out_b   = (const float*)d_in[19];
  float* ws  = (float*)d_ws;
  float* out = (float*)d_out;

  short* Ahi    = (short*)(ws + OFF_ST);
  short* Alo    = Ahi + (size_t)V_ * KP;
  short* Bthi   = (short*)(ws + OFF_BT);
  short* Btlo   = Bthi + (size_t)NCOL * KP;
  short* awt_hi = (short*)(ws + OFF_AWT);
  short* awt_lo = awt_hi + 128 * 128;
  float* partials = ws + OFF_BT;   // Bt region is dead after gemm

  pack_kernel<<<1299, 256, 0, stream>>>(fw_gw, fw_gb, fw_cw, fw_cb,
                                        bw_gw, bw_gb, bw_cw, bw_cb, ws);
  pack_bt<<<(NCOL * KP + 128 * 128 + 255) / 256, 256, 0, stream>>>(
      ws + OFF_WXP, Bthi, Btlo, att_w, awt_hi, awt_lo);
  pack_emb<<<(int)(((size_t)V_ * KP + 255) / 256), 256, 0, stream>>>(emb, Ahi, Alo);

  gemm_mfma<<<2346, 256, 0, stream>>>(Ahi, Alo, Bthi, Btlo, ws + OFF_PROJ);

  recur_kernel<<<512, 256, 0, stream>>>(ctx, endseq, ctx_len, end_len,
                                        ws + OFF_PROJ, ws + OFF_UALL,
                                        ws + OFF_BIAS, ws + OFF_ST);

  attn_kernel<<<768, 256, 0, stream>>>(ws + OFF_ST, awt_hi, awt_lo,
                                       att_v, att_b, partials);
  attn_merge_kernel<<<512, 128, 0, stream>>>(partials, ws + OFF_FEATS);

  head_kernel<<<128, 128, 0, stream>>>(ws + OFF_FEATS, hid_w, hid_b,
                                       out_w, out_b, out);
}